// Round 3
// baseline (11023.475 us; speedup 1.0000x reference)
//
#include <hip/hip_runtime.h>
#include <math.h>

#define BB 4
#define HHH 128
#define WWW 128
#define AANG 96
#define DDET 128
#define TSTEP 182
#define M_P (BB*HHH*WWW)   // 65536
#define M_D (BB*AANG*DDET) // 49152
#define INV_OPN (1.0f/128.0f)
#define NB 512
#define NT (NB*256)        // 131072 threads
#define NWAVES (NT/64)     // 2048 waves

typedef __bf16 bf16x8 __attribute__((ext_vector_type(8)));
typedef float  f32x4  __attribute__((ext_vector_type(4)));

__device__ __forceinline__ void split_store(__bf16* hi, __bf16* lo, int off, float v) {
    __bf16 h = (__bf16)v;
    hi[off] = h;
    lo[off] = (__bf16)(v - (float)h);
}

// ---- device-scope grid barrier (all NB blocks co-resident: 2 blocks/CU) ----
__device__ __forceinline__ void gbar(unsigned* bcnt, unsigned* bgen, unsigned& mygen) {
    __syncthreads();
    if (threadIdx.x == 0) {
        __threadfence();
        unsigned arrived = __hip_atomic_fetch_add(bcnt, 1u, __ATOMIC_ACQ_REL, __HIP_MEMORY_SCOPE_AGENT);
        if (arrived == NB - 1) {
            __hip_atomic_store(bcnt, 0u, __ATOMIC_RELAXED, __HIP_MEMORY_SCOPE_AGENT);
            __hip_atomic_fetch_add(bgen, 1u, __ATOMIC_ACQ_REL, __HIP_MEMORY_SCOPE_AGENT);
        } else {
            while (__hip_atomic_load(bgen, __ATOMIC_ACQUIRE, __HIP_MEMORY_SCOPE_AGENT) <= mygen) {
                __builtin_amdgcn_s_sleep(2);
            }
        }
    }
    mygen++;
    __syncthreads();
}

// ================= conv core: implicit GEMM, 16x16x32 bf16 MFMA, bf16x3 split =================
template<int CIP, int NCH, int NCOT, int IH>
__device__ __forceinline__ void conv_core(
        const __bf16* __restrict__ Ahi, const __bf16* __restrict__ Alo,
        const __bf16* __restrict__ Whi, const __bf16* __restrict__ Wlo,
        int mtile, f32x4 acc[NCOT])
{
    const int IW = 128;
    const int COP = NCOT * 16;
    int lane = threadIdx.x & 63;
    int n16  = lane & 15;
    int quad = lane >> 4;
    int p0  = mtile * 16;
    int b   = p0 / (IH * IW);
    int rem = p0 - b * (IH * IW);
    int ty  = rem >> 7;
    int tx0 = rem & 127;
    #pragma unroll
    for (int c = 0; c < NCH; ++c) {
        int tap = (CIP == 32) ? c : (c * 4 + quad);
        int dy = tap / 3 - 1;
        int dx = tap % 3 - 1;
        int yy = ty + dy;
        int xx = tx0 + n16 + dx;
        bool valid = (tap < 9) && (yy >= 0) && (yy < IH) && (xx >= 0) && (xx < IW);
        bf16x8 a_h = {};
        bf16x8 a_l = {};
        if (valid) {
            size_t off = (size_t)(b * IH * IW + yy * IW + xx) * CIP
                       + ((CIP == 32) ? (quad * 8) : 0);
            a_h = *(const bf16x8*)(Ahi + off);
            a_l = *(const bf16x8*)(Alo + off);
        }
        #pragma unroll
        for (int ct = 0; ct < NCOT; ++ct) {
            size_t woff = ((size_t)tap * COP + ct * 16 + n16) * CIP
                        + ((CIP == 32) ? (quad * 8) : 0);
            bf16x8 b_h = *(const bf16x8*)(Whi + woff);
            bf16x8 b_l = *(const bf16x8*)(Wlo + woff);
            acc[ct] = __builtin_amdgcn_mfma_f32_16x16x32_bf16(a_h, b_h, acc[ct], 0, 0, 0);
            acc[ct] = __builtin_amdgcn_mfma_f32_16x16x32_bf16(a_h, b_l, acc[ct], 0, 0, 0);
            acc[ct] = __builtin_amdgcn_mfma_f32_16x16x32_bf16(a_l, b_h, acc[ct], 0, 0, 0);
        }
    }
}

__device__ __forceinline__ void epi_ab(const f32x4* acc, const float* __restrict__ bias,
                                       __bf16* Ohi, __bf16* Olo, int mt) {
    int lane = threadIdx.x & 63;
    int n16 = lane & 15;
    int quad = lane >> 4;
    #pragma unroll
    for (int ct = 0; ct < 2; ++ct) {
        float bv = bias[ct * 16 + n16];
        #pragma unroll
        for (int r = 0; r < 4; ++r) {
            float v = fmaxf(acc[ct][r] + bv, 0.f);
            int m = mt * 16 + quad * 4 + r;
            split_store(Ohi, Olo, m * 32 + ct * 16 + n16, v);
        }
    }
}

__global__ __launch_bounds__(256, 2) void cp_persist_k(
    const float* __restrict__ y, const float* __restrict__ sigma,
    const float* __restrict__ tau, const float* __restrict__ theta,
    const float* __restrict__ dw1, const float* __restrict__ db1,
    const float* __restrict__ dw2, const float* __restrict__ db2,
    const float* __restrict__ dw3, const float* __restrict__ db3,
    const float* __restrict__ pw1, const float* __restrict__ pb1,
    const float* __restrict__ pw2, const float* __restrict__ pb2,
    const float* __restrict__ pw3, const float* __restrict__ pb3,
    float* __restrict__ out,
    unsigned* bcnt, unsigned* bgen,
    float* primal_f, float* dual_f, float* pbar1, float* dual0,
    __bf16* cat_d_hi, __bf16* cat_d_lo, __bf16* cat_p_hi, __bf16* cat_p_lo,
    __bf16* hidA_hi, __bf16* hidA_lo, __bf16* hidB_hi, __bf16* hidB_lo,
    __bf16* wT)
{
    __shared__ float cs[AANG], ss[AANG];
    const int tid = blockIdx.x * 256 + threadIdx.x;
    const int gw = tid >> 6;
    unsigned mygen = 0;

    __bf16* d1h = wT;            __bf16* d1l = d1h + 3072;
    __bf16* d2h = d1l + 3072;    __bf16* d2l = d2h + 9216;
    __bf16* d3h = d2l + 9216;    __bf16* d3l = d3h + 4608;
    __bf16* p1h = d3l + 4608;    __bf16* p1l = p1h + 3072;
    __bf16* p2h = p1l + 3072;    __bf16* p2l = p2h + 9216;
    __bf16* p3h = p2l + 9216;    __bf16* p3l = p3h + 4608;

    if (threadIdx.x < AANG) {
        double ang = (double)threadIdx.x * M_PI / (double)AANG;
        cs[threadIdx.x] = (float)cos(ang);
        ss[threadIdx.x] = (float)sin(ang);
    }

    // ---------------- setup: zero state, build cat buffers, transpose/split weights ----------------
    for (int i = tid; i < M_P * 5; i += NT) primal_f[i] = 0.f;
    for (int i = tid; i < M_D * 5; i += NT) dual_f[i] = 0.f;
    for (int i = tid; i < M_P; i += NT) pbar1[i] = 0.f;
    for (int i = tid; i < M_D * 8; i += NT) {
        int ch = i & 7;
        float v = (ch == 6) ? y[i >> 3] : 0.f;
        split_store(cat_d_hi, cat_d_lo, i, v);
    }
    for (int i = tid; i < M_P * 8; i += NT) { cat_p_hi[i] = (__bf16)0.f; cat_p_lo[i] = (__bf16)0.f; }
    for (int i = tid; i < 3072; i += NT) { int tap = i >> 8, co = (i >> 3) & 31, ci = i & 7;
        float v = (tap < 9 && ci < 7) ? dw1[(tap * 7 + ci) * 32 + co] : 0.f; split_store(d1h, d1l, i, v); }
    for (int i = tid; i < 9216; i += NT) { int tap = i >> 10, co = (i >> 5) & 31, ci = i & 31;
        float v = dw2[(tap * 32 + ci) * 32 + co]; split_store(d2h, d2l, i, v); }
    for (int i = tid; i < 4608; i += NT) { int tap = i >> 9, co = (i >> 5) & 15, ci = i & 31;
        float v = (co < 5) ? dw3[(tap * 32 + ci) * 5 + co] : 0.f; split_store(d3h, d3l, i, v); }
    for (int i = tid; i < 3072; i += NT) { int tap = i >> 8, co = (i >> 3) & 31, ci = i & 7;
        float v = (tap < 9 && ci < 6) ? pw1[(tap * 6 + ci) * 32 + co] : 0.f; split_store(p1h, p1l, i, v); }
    for (int i = tid; i < 9216; i += NT) { int tap = i >> 10, co = (i >> 5) & 31, ci = i & 31;
        float v = pw2[(tap * 32 + ci) * 32 + co]; split_store(p2h, p2l, i, v); }
    for (int i = tid; i < 4608; i += NT) { int tap = i >> 9, co = (i >> 5) & 15, ci = i & 31;
        float v = (co < 5) ? pw3[(tap * 32 + ci) * 5 + co] : 0.f; split_store(p3h, p3l, i, v); }

    gbar(bcnt, bgen, mygen);

    const int MT_D = M_D / 16;   // 3072
    const int MT_P = M_P / 16;   // 4096

    for (int it = 0; it < 10; ++it) {
        // ---- S1: radon forward (t-split x2, pair-combine) -> cat_d ch5 ----
        if (tid < 2 * M_D) {
            int pix = tid >> 1, h = tid & 1;
            int d = pix & 127;
            int b = pix / (AANG * DDET);
            int a = (pix - b * AANG * DDET) >> 7;
            float c = cs[a], sn = ss[a];
            float s = (float)d - 63.5f;
            float scx = s * c, ssy = s * sn;
            const float* ib = pbar1 + b * (HHH * WWW);
            float acc = 0.f;
            int t0 = h * 91;
            for (int tt = t0; tt < t0 + 91; ++tt) {
                float t = (float)tt - 90.5f;
                float xi = (scx - t * sn) + 63.5f;
                float yi = (ssy + t * c) + 63.5f;
                float x0f = floorf(xi), y0f = floorf(yi);
                float wx = xi - x0f, wy = yi - y0f;
                int x0 = (int)x0f, y0 = (int)y0f;
                int x1 = x0 + 1, y1 = y0 + 1;
                bool xv0 = (x0 >= 0) & (x0 < WWW);
                bool xv1 = (x1 >= 0) & (x1 < WWW);
                bool yv0 = (y0 >= 0) & (y0 < HHH);
                bool yv1 = (y1 >= 0) & (y1 < HHH);
                float v00 = (yv0 & xv0) ? ib[y0 * WWW + x0] : 0.f;
                float v01 = (yv0 & xv1) ? ib[y0 * WWW + x1] : 0.f;
                float v10 = (yv1 & xv0) ? ib[y1 * WWW + x0] : 0.f;
                float v11 = (yv1 & xv1) ? ib[y1 * WWW + x1] : 0.f;
                acc += v00 * (1.f - wy) * (1.f - wx) + v01 * (1.f - wy) * wx
                     + v10 * wy * (1.f - wx) + v11 * wy * wx;
            }
            float other = __shfl_xor(acc, 1);
            if (h == 0) split_store(cat_d_hi, cat_d_lo, pix * 8 + 5, (acc + other) * INV_OPN);
        }
        gbar(bcnt, bgen, mygen);

        // ---- S2: dual conv1 ----
        for (int mt = gw; mt < MT_D; mt += NWAVES) {
            f32x4 acc[2] = {};
            conv_core<8, 3, 2, AANG>(cat_d_hi, cat_d_lo, d1h, d1l, mt, acc);
            epi_ab(acc, db1, hidA_hi, hidA_lo, mt);
        }
        gbar(bcnt, bgen, mygen);

        // ---- S3: dual conv2 ----
        for (int mt = gw; mt < MT_D; mt += NWAVES) {
            f32x4 acc[2] = {};
            conv_core<32, 9, 2, AANG>(hidA_hi, hidA_lo, d2h, d2l, mt, acc);
            epi_ab(acc, db2, hidB_hi, hidB_lo, mt);
        }
        gbar(bcnt, bgen, mygen);

        // ---- S4: dual conv3 + dual update ----
        {
            float sg = *sigma;
            for (int mt = gw; mt < MT_D; mt += NWAVES) {
                f32x4 acc[1] = {};
                conv_core<32, 9, 1, AANG>(hidB_hi, hidB_lo, d3h, d3l, mt, acc);
                int lane = threadIdx.x & 63;
                int n16 = lane & 15;
                int quad = lane >> 4;
                if (n16 < 5) {
                    float bv = db3[n16];
                    #pragma unroll
                    for (int r = 0; r < 4; ++r) {
                        int m = mt * 16 + quad * 4 + r;
                        float v = acc[0][r] + bv;
                        float dn = dual_f[m * 5 + n16] + sg * v;
                        dual_f[m * 5 + n16] = dn;
                        split_store(cat_d_hi, cat_d_lo, m * 8 + n16, dn);
                        if (n16 == 0) dual0[m] = dn;
                    }
                }
            }
        }
        gbar(bcnt, bgen, mygen);

        // ---- S5: radon adjoint (a-split x2, pair-combine) -> cat_p ch5 ----
        if (tid < 2 * M_P) {
            int pix = tid >> 1, h = tid & 1;
            int x = pix & 127;
            int yv = (pix >> 7) & 127;
            int b = pix >> 14;
            float px = (float)x - 63.5f;
            float py = (float)yv - 63.5f;
            const float* sb = dual0 + b * (AANG * DDET);
            float acc = 0.f;
            int a0 = h * 48;
            for (int a = a0; a < a0 + 48; ++a) {
                float det = px * cs[a] + py * ss[a] + 63.5f;
                float dh = floorf(det);
                float w = det - dh;
                int d0 = (int)dh;
                int d1 = d0 + 1;
                float v0 = (d0 >= 0 && d0 < DDET) ? sb[a * DDET + d0] : 0.f;
                float v1 = (d1 >= 0 && d1 < DDET) ? sb[a * DDET + d1] : 0.f;
                acc += v0 * (1.f - w) + v1 * w;
            }
            float other = __shfl_xor(acc, 1);
            if (h == 0) split_store(cat_p_hi, cat_p_lo, pix * 8 + 5, (acc + other) * INV_OPN);
        }
        gbar(bcnt, bgen, mygen);

        // ---- S6: primal conv1 ----
        for (int mt = gw; mt < MT_P; mt += NWAVES) {
            f32x4 acc[2] = {};
            conv_core<8, 3, 2, HHH>(cat_p_hi, cat_p_lo, p1h, p1l, mt, acc);
            epi_ab(acc, pb1, hidA_hi, hidA_lo, mt);
        }
        gbar(bcnt, bgen, mygen);

        // ---- S7: primal conv2 ----
        for (int mt = gw; mt < MT_P; mt += NWAVES) {
            f32x4 acc[2] = {};
            conv_core<32, 9, 2, HHH>(hidA_hi, hidA_lo, p2h, p2l, mt, acc);
            epi_ab(acc, pb2, hidB_hi, hidB_lo, mt);
        }
        gbar(bcnt, bgen, mygen);

        // ---- S8: primal conv3 + primal/primal_bar update ----
        {
            float ta = *tau;
            float th = *theta;
            for (int mt = gw; mt < MT_P; mt += NWAVES) {
                f32x4 acc[1] = {};
                conv_core<32, 9, 1, HHH>(hidB_hi, hidB_lo, p3h, p3l, mt, acc);
                int lane = threadIdx.x & 63;
                int n16 = lane & 15;
                int quad = lane >> 4;
                if (n16 < 5) {
                    float bv = pb3[n16];
                    #pragma unroll
                    for (int r = 0; r < 4; ++r) {
                        int m = mt * 16 + quad * 4 + r;
                        float v = acc[0][r] + bv;
                        float pold = primal_f[m * 5 + n16];
                        float pn = pold + ta * v;
                        primal_f[m * 5 + n16] = pn;
                        split_store(cat_p_hi, cat_p_lo, m * 8 + n16, pn);
                        if (n16 == 1) pbar1[m] = pn + th * (pn - pold);
                    }
                }
            }
        }
        gbar(bcnt, bgen, mygen);
    }

    // ---- extract ch0 ----
    if (tid < M_P) out[tid] = primal_f[tid * 5];
}

extern "C" void kernel_launch(void* const* d_in, const int* in_sizes, int n_in,
                              void* d_out, int out_size, void* d_ws, size_t ws_size,
                              hipStream_t stream) {
    const float* y     = (const float*)d_in[0];
    const float* sigma = (const float*)d_in[1];
    const float* tau   = (const float*)d_in[2];
    const float* theta = (const float*)d_in[3];
    const float* dw1 = (const float*)d_in[4];
    const float* db1 = (const float*)d_in[5];
    const float* dw2 = (const float*)d_in[6];
    const float* db2 = (const float*)d_in[7];
    const float* dw3 = (const float*)d_in[8];
    const float* db3 = (const float*)d_in[9];
    const float* pw1 = (const float*)d_in[10];
    const float* pb1 = (const float*)d_in[11];
    const float* pw2 = (const float*)d_in[12];
    const float* pb2 = (const float*)d_in[13];
    const float* pw3 = (const float*)d_in[14];
    const float* pb3 = (const float*)d_in[15];

    float* ws = (float*)d_ws;
    unsigned* bcnt = (unsigned*)ws;          // barrier words in separate cache lines
    unsigned* bgen = (unsigned*)(ws + 64);
    float* primal_f = ws + 128;              // M_P*5
    float* dual_f   = primal_f + M_P * 5;    // M_D*5
    float* pbar1    = dual_f + M_D * 5;      // M_P
    float* dual0    = pbar1 + M_P;           // M_D
    __bf16* bf = (__bf16*)(dual0 + M_D);
    __bf16* cat_d_hi = bf;                   // M_D*8
    __bf16* cat_d_lo = cat_d_hi + M_D * 8;
    __bf16* cat_p_hi = cat_d_lo + M_D * 8;   // M_P*8
    __bf16* cat_p_lo = cat_p_hi + M_P * 8;
    __bf16* hidA_hi  = cat_p_lo + M_P * 8;   // M_P*32
    __bf16* hidA_lo  = hidA_hi + M_P * 32;
    __bf16* hidB_hi  = hidA_lo + M_P * 32;
    __bf16* hidB_lo  = hidB_hi + M_P * 32;
    __bf16* wT       = hidB_lo + M_P * 32;   // 67584

    // only the barrier words need pre-zeroing; everything else is initialized in-kernel
    hipMemsetAsync(ws, 0, 512, stream);

    cp_persist_k<<<NB, 256, 0, stream>>>(
        y, sigma, tau, theta,
        dw1, db1, dw2, db2, dw3, db3,
        pw1, pb1, pw2, pb2, pw3, pb3,
        (float*)d_out, bcnt, bgen,
        primal_f, dual_f, pbar1, dual0,
        cat_d_hi, cat_d_lo, cat_p_hi, cat_p_lo,
        hidA_hi, hidA_lo, hidB_hi, hidB_lo, wT);
}

// Round 4
// 6122.837 us; speedup vs baseline: 1.8004x; 1.8004x over previous
//
#include <hip/hip_runtime.h>
#include <math.h>

#define BB 4
#define HHH 128
#define WWW 128
#define AANG 96
#define DDET 128
#define TSTEP 182
#define M_P (BB*HHH*WWW)   // 65536
#define M_D (BB*AANG*DDET) // 49152
#define INV_OPN (1.0f/128.0f)
#define NB 512
#define NT (NB*256)        // 131072 threads
#define NWAVES (NT/64)     // 2048 waves

typedef __bf16 bf16x8 __attribute__((ext_vector_type(8)));
typedef float  f32x4  __attribute__((ext_vector_type(4)));

__device__ __forceinline__ void split_store(__bf16* hi, __bf16* lo, int off, float v) {
    __bf16 h = (__bf16)v;
    hi[off] = h;
    lo[off] = (__bf16)(v - (float)h);
}

// ---- device-scope grid barrier, monotonic counter, relaxed spin ----
// Key gfx950 facts: agent-scope acquire => buffer_inv (XCD-L2 flash invalidate),
// agent-scope release => buffer_wbl2. These must execute ONCE per block per
// barrier, never inside the spin loop and never per-arrival as acq_rel RMW.
__device__ __forceinline__ void gbar(unsigned* bcnt, unsigned& bar_no) {
    __syncthreads();
    bar_no++;
    if (threadIdx.x == 0) {
        __builtin_amdgcn_fence(__ATOMIC_RELEASE, "agent");   // wb dirty L2 lines once
        __hip_atomic_fetch_add(bcnt, 1u, __ATOMIC_RELAXED, __HIP_MEMORY_SCOPE_AGENT);
        while (__hip_atomic_load(bcnt, __ATOMIC_RELAXED, __HIP_MEMORY_SCOPE_AGENT) < bar_no * NB) {
            __builtin_amdgcn_s_sleep(2);
        }
    }
    __syncthreads();
    __builtin_amdgcn_fence(__ATOMIC_ACQUIRE, "agent");       // invalidate once, all threads (compiler order)
}

// ================= conv core: implicit GEMM, 16x16x32 bf16 MFMA, bf16x3 split =================
template<int CIP, int NCH, int NCOT, int IH>
__device__ __forceinline__ void conv_core(
        const __bf16* __restrict__ Ahi, const __bf16* __restrict__ Alo,
        const __bf16* __restrict__ Whi, const __bf16* __restrict__ Wlo,
        int mtile, f32x4 acc[NCOT])
{
    const int IW = 128;
    const int COP = NCOT * 16;
    int lane = threadIdx.x & 63;
    int n16  = lane & 15;
    int quad = lane >> 4;
    int p0  = mtile * 16;
    int b   = p0 / (IH * IW);
    int rem = p0 - b * (IH * IW);
    int ty  = rem >> 7;
    int tx0 = rem & 127;
    #pragma unroll
    for (int c = 0; c < NCH; ++c) {
        int tap = (CIP == 32) ? c : (c * 4 + quad);
        int dy = tap / 3 - 1;
        int dx = tap % 3 - 1;
        int yy = ty + dy;
        int xx = tx0 + n16 + dx;
        bool valid = (tap < 9) && (yy >= 0) && (yy < IH) && (xx >= 0) && (xx < IW);
        bf16x8 a_h = {};
        bf16x8 a_l = {};
        if (valid) {
            size_t off = (size_t)(b * IH * IW + yy * IW + xx) * CIP
                       + ((CIP == 32) ? (quad * 8) : 0);
            a_h = *(const bf16x8*)(Ahi + off);
            a_l = *(const bf16x8*)(Alo + off);
        }
        #pragma unroll
        for (int ct = 0; ct < NCOT; ++ct) {
            size_t woff = ((size_t)tap * COP + ct * 16 + n16) * CIP
                        + ((CIP == 32) ? (quad * 8) : 0);
            bf16x8 b_h = *(const bf16x8*)(Whi + woff);
            bf16x8 b_l = *(const bf16x8*)(Wlo + woff);
            acc[ct] = __builtin_amdgcn_mfma_f32_16x16x32_bf16(a_h, b_h, acc[ct], 0, 0, 0);
            acc[ct] = __builtin_amdgcn_mfma_f32_16x16x32_bf16(a_h, b_l, acc[ct], 0, 0, 0);
            acc[ct] = __builtin_amdgcn_mfma_f32_16x16x32_bf16(a_l, b_h, acc[ct], 0, 0, 0);
        }
    }
}

__device__ __forceinline__ void epi_ab(const f32x4* acc, const float* __restrict__ bias,
                                       __bf16* Ohi, __bf16* Olo, int mt) {
    int lane = threadIdx.x & 63;
    int n16 = lane & 15;
    int quad = lane >> 4;
    #pragma unroll
    for (int ct = 0; ct < 2; ++ct) {
        float bv = bias[ct * 16 + n16];
        #pragma unroll
        for (int r = 0; r < 4; ++r) {
            float v = fmaxf(acc[ct][r] + bv, 0.f);
            int m = mt * 16 + quad * 4 + r;
            split_store(Ohi, Olo, m * 32 + ct * 16 + n16, v);
        }
    }
}

__global__ __launch_bounds__(256, 2) void cp_persist_k(
    const float* __restrict__ y, const float* __restrict__ sigma,
    const float* __restrict__ tau, const float* __restrict__ theta,
    const float* __restrict__ dw1, const float* __restrict__ db1,
    const float* __restrict__ dw2, const float* __restrict__ db2,
    const float* __restrict__ dw3, const float* __restrict__ db3,
    const float* __restrict__ pw1, const float* __restrict__ pb1,
    const float* __restrict__ pw2, const float* __restrict__ pb2,
    const float* __restrict__ pw3, const float* __restrict__ pb3,
    float* __restrict__ out,
    unsigned* bcnt,
    float* primal_f, float* dual_f, float* pbar1, float* dual0,
    __bf16* cat_d_hi, __bf16* cat_d_lo, __bf16* cat_p_hi, __bf16* cat_p_lo,
    __bf16* hidA_hi, __bf16* hidA_lo, __bf16* hidB_hi, __bf16* hidB_lo,
    __bf16* wT)
{
    __shared__ float cs[AANG], ss[AANG];
    const int tid = blockIdx.x * 256 + threadIdx.x;
    const int gw = tid >> 6;
    unsigned bar_no = 0;

    __bf16* d1h = wT;            __bf16* d1l = d1h + 3072;
    __bf16* d2h = d1l + 3072;    __bf16* d2l = d2h + 9216;
    __bf16* d3h = d2l + 9216;    __bf16* d3l = d3h + 4608;
    __bf16* p1h = d3l + 4608;    __bf16* p1l = p1h + 3072;
    __bf16* p2h = p1l + 3072;    __bf16* p2l = p2h + 9216;
    __bf16* p3h = p2l + 9216;    __bf16* p3l = p3h + 4608;

    if (threadIdx.x < AANG) {
        double ang = (double)threadIdx.x * M_PI / (double)AANG;
        cs[threadIdx.x] = (float)cos(ang);
        ss[threadIdx.x] = (float)sin(ang);
    }

    // ---------------- setup: zero state, build cat buffers, transpose/split weights ----------------
    for (int i = tid; i < M_P * 5; i += NT) primal_f[i] = 0.f;
    for (int i = tid; i < M_D * 5; i += NT) dual_f[i] = 0.f;
    for (int i = tid; i < M_P; i += NT) pbar1[i] = 0.f;
    for (int i = tid; i < M_D * 8; i += NT) {
        int ch = i & 7;
        float v = (ch == 6) ? y[i >> 3] : 0.f;
        split_store(cat_d_hi, cat_d_lo, i, v);
    }
    for (int i = tid; i < M_P * 8; i += NT) { cat_p_hi[i] = (__bf16)0.f; cat_p_lo[i] = (__bf16)0.f; }
    for (int i = tid; i < 3072; i += NT) { int tap = i >> 8, co = (i >> 3) & 31, ci = i & 7;
        float v = (tap < 9 && ci < 7) ? dw1[(tap * 7 + ci) * 32 + co] : 0.f; split_store(d1h, d1l, i, v); }
    for (int i = tid; i < 9216; i += NT) { int tap = i >> 10, co = (i >> 5) & 31, ci = i & 31;
        float v = dw2[(tap * 32 + ci) * 32 + co]; split_store(d2h, d2l, i, v); }
    for (int i = tid; i < 4608; i += NT) { int tap = i >> 9, co = (i >> 5) & 15, ci = i & 31;
        float v = (co < 5) ? dw3[(tap * 32 + ci) * 5 + co] : 0.f; split_store(d3h, d3l, i, v); }
    for (int i = tid; i < 3072; i += NT) { int tap = i >> 8, co = (i >> 3) & 31, ci = i & 7;
        float v = (tap < 9 && ci < 6) ? pw1[(tap * 6 + ci) * 32 + co] : 0.f; split_store(p1h, p1l, i, v); }
    for (int i = tid; i < 9216; i += NT) { int tap = i >> 10, co = (i >> 5) & 31, ci = i & 31;
        float v = pw2[(tap * 32 + ci) * 32 + co]; split_store(p2h, p2l, i, v); }
    for (int i = tid; i < 4608; i += NT) { int tap = i >> 9, co = (i >> 5) & 15, ci = i & 31;
        float v = (co < 5) ? pw3[(tap * 32 + ci) * 5 + co] : 0.f; split_store(p3h, p3l, i, v); }

    gbar(bcnt, bar_no);

    const int MT_D = M_D / 16;   // 3072
    const int MT_P = M_P / 16;   // 4096

    for (int it = 0; it < 10; ++it) {
        // ---- S1: radon forward (t-split x2, pair-combine) -> cat_d ch5 ----
        if (tid < 2 * M_D) {
            int pix = tid >> 1, h = tid & 1;
            int d = pix & 127;
            int b = pix / (AANG * DDET);
            int a = (pix - b * AANG * DDET) >> 7;
            float c = cs[a], sn = ss[a];
            float s = (float)d - 63.5f;
            float scx = s * c, ssy = s * sn;
            const float* ib = pbar1 + b * (HHH * WWW);
            float acc = 0.f;
            int t0 = h * 91;
            for (int tt = t0; tt < t0 + 91; ++tt) {
                float t = (float)tt - 90.5f;
                float xi = (scx - t * sn) + 63.5f;
                float yi = (ssy + t * c) + 63.5f;
                float x0f = floorf(xi), y0f = floorf(yi);
                float wx = xi - x0f, wy = yi - y0f;
                int x0 = (int)x0f, y0 = (int)y0f;
                int x1 = x0 + 1, y1 = y0 + 1;
                bool xv0 = (x0 >= 0) & (x0 < WWW);
                bool xv1 = (x1 >= 0) & (x1 < WWW);
                bool yv0 = (y0 >= 0) & (y0 < HHH);
                bool yv1 = (y1 >= 0) & (y1 < HHH);
                float v00 = (yv0 & xv0) ? ib[y0 * WWW + x0] : 0.f;
                float v01 = (yv0 & xv1) ? ib[y0 * WWW + x1] : 0.f;
                float v10 = (yv1 & xv0) ? ib[y1 * WWW + x0] : 0.f;
                float v11 = (yv1 & xv1) ? ib[y1 * WWW + x1] : 0.f;
                acc += v00 * (1.f - wy) * (1.f - wx) + v01 * (1.f - wy) * wx
                     + v10 * wy * (1.f - wx) + v11 * wy * wx;
            }
            float other = __shfl_xor(acc, 1);
            if (h == 0) split_store(cat_d_hi, cat_d_lo, pix * 8 + 5, (acc + other) * INV_OPN);
        }
        gbar(bcnt, bar_no);

        // ---- S2: dual conv1 ----
        for (int mt = gw; mt < MT_D; mt += NWAVES) {
            f32x4 acc[2] = {};
            conv_core<8, 3, 2, AANG>(cat_d_hi, cat_d_lo, d1h, d1l, mt, acc);
            epi_ab(acc, db1, hidA_hi, hidA_lo, mt);
        }
        gbar(bcnt, bar_no);

        // ---- S3: dual conv2 ----
        for (int mt = gw; mt < MT_D; mt += NWAVES) {
            f32x4 acc[2] = {};
            conv_core<32, 9, 2, AANG>(hidA_hi, hidA_lo, d2h, d2l, mt, acc);
            epi_ab(acc, db2, hidB_hi, hidB_lo, mt);
        }
        gbar(bcnt, bar_no);

        // ---- S4: dual conv3 + dual update ----
        {
            float sg = *sigma;
            for (int mt = gw; mt < MT_D; mt += NWAVES) {
                f32x4 acc[1] = {};
                conv_core<32, 9, 1, AANG>(hidB_hi, hidB_lo, d3h, d3l, mt, acc);
                int lane = threadIdx.x & 63;
                int n16 = lane & 15;
                int quad = lane >> 4;
                if (n16 < 5) {
                    float bv = db3[n16];
                    #pragma unroll
                    for (int r = 0; r < 4; ++r) {
                        int m = mt * 16 + quad * 4 + r;
                        float v = acc[0][r] + bv;
                        float dn = dual_f[m * 5 + n16] + sg * v;
                        dual_f[m * 5 + n16] = dn;
                        split_store(cat_d_hi, cat_d_lo, m * 8 + n16, dn);
                        if (n16 == 0) dual0[m] = dn;
                    }
                }
            }
        }
        gbar(bcnt, bar_no);

        // ---- S5: radon adjoint (a-split x2, pair-combine) -> cat_p ch5 ----
        if (tid < 2 * M_P) {
            int pix = tid >> 1, h = tid & 1;
            int x = pix & 127;
            int yv = (pix >> 7) & 127;
            int b = pix >> 14;
            float px = (float)x - 63.5f;
            float py = (float)yv - 63.5f;
            const float* sb = dual0 + b * (AANG * DDET);
            float acc = 0.f;
            int a0 = h * 48;
            for (int a = a0; a < a0 + 48; ++a) {
                float det = px * cs[a] + py * ss[a] + 63.5f;
                float dh = floorf(det);
                float w = det - dh;
                int d0 = (int)dh;
                int d1 = d0 + 1;
                float v0 = (d0 >= 0 && d0 < DDET) ? sb[a * DDET + d0] : 0.f;
                float v1 = (d1 >= 0 && d1 < DDET) ? sb[a * DDET + d1] : 0.f;
                acc += v0 * (1.f - w) + v1 * w;
            }
            float other = __shfl_xor(acc, 1);
            if (h == 0) split_store(cat_p_hi, cat_p_lo, pix * 8 + 5, (acc + other) * INV_OPN);
        }
        gbar(bcnt, bar_no);

        // ---- S6: primal conv1 ----
        for (int mt = gw; mt < MT_P; mt += NWAVES) {
            f32x4 acc[2] = {};
            conv_core<8, 3, 2, HHH>(cat_p_hi, cat_p_lo, p1h, p1l, mt, acc);
            epi_ab(acc, pb1, hidA_hi, hidA_lo, mt);
        }
        gbar(bcnt, bar_no);

        // ---- S7: primal conv2 ----
        for (int mt = gw; mt < MT_P; mt += NWAVES) {
            f32x4 acc[2] = {};
            conv_core<32, 9, 2, HHH>(hidA_hi, hidA_lo, p2h, p2l, mt, acc);
            epi_ab(acc, pb2, hidB_hi, hidB_lo, mt);
        }
        gbar(bcnt, bar_no);

        // ---- S8: primal conv3 + primal/primal_bar update ----
        {
            float ta = *tau;
            float th = *theta;
            for (int mt = gw; mt < MT_P; mt += NWAVES) {
                f32x4 acc[1] = {};
                conv_core<32, 9, 1, HHH>(hidB_hi, hidB_lo, p3h, p3l, mt, acc);
                int lane = threadIdx.x & 63;
                int n16 = lane & 15;
                int quad = lane >> 4;
                if (n16 < 5) {
                    float bv = pb3[n16];
                    #pragma unroll
                    for (int r = 0; r < 4; ++r) {
                        int m = mt * 16 + quad * 4 + r;
                        float v = acc[0][r] + bv;
                        float pold = primal_f[m * 5 + n16];
                        float pn = pold + ta * v;
                        primal_f[m * 5 + n16] = pn;
                        split_store(cat_p_hi, cat_p_lo, m * 8 + n16, pn);
                        if (n16 == 1) pbar1[m] = pn + th * (pn - pold);
                    }
                }
            }
        }
        gbar(bcnt, bar_no);
    }

    // ---- extract ch0 ----
    if (tid < M_P) out[tid] = primal_f[tid * 5];
}

extern "C" void kernel_launch(void* const* d_in, const int* in_sizes, int n_in,
                              void* d_out, int out_size, void* d_ws, size_t ws_size,
                              hipStream_t stream) {
    const float* y     = (const float*)d_in[0];
    const float* sigma = (const float*)d_in[1];
    const float* tau   = (const float*)d_in[2];
    const float* theta = (const float*)d_in[3];
    const float* dw1 = (const float*)d_in[4];
    const float* db1 = (const float*)d_in[5];
    const float* dw2 = (const float*)d_in[6];
    const float* db2 = (const float*)d_in[7];
    const float* dw3 = (const float*)d_in[8];
    const float* db3 = (const float*)d_in[9];
    const float* pw1 = (const float*)d_in[10];
    const float* pb1 = (const float*)d_in[11];
    const float* pw2 = (const float*)d_in[12];
    const float* pb2 = (const float*)d_in[13];
    const float* pw3 = (const float*)d_in[14];
    const float* pb3 = (const float*)d_in[15];

    float* ws = (float*)d_ws;
    unsigned* bcnt = (unsigned*)ws;          // barrier counter (own cache line)
    float* primal_f = ws + 128;              // M_P*5
    float* dual_f   = primal_f + M_P * 5;    // M_D*5
    float* pbar1    = dual_f + M_D * 5;      // M_P
    float* dual0    = pbar1 + M_P;           // M_D
    __bf16* bf = (__bf16*)(dual0 + M_D);
    __bf16* cat_d_hi = bf;                   // M_D*8
    __bf16* cat_d_lo = cat_d_hi + M_D * 8;
    __bf16* cat_p_hi = cat_d_lo + M_D * 8;   // M_P*8
    __bf16* cat_p_lo = cat_p_hi + M_P * 8;
    __bf16* hidA_hi  = cat_p_lo + M_P * 8;   // M_P*32
    __bf16* hidA_lo  = hidA_hi + M_P * 32;
    __bf16* hidB_hi  = hidA_lo + M_P * 32;
    __bf16* hidB_lo  = hidB_hi + M_P * 32;
    __bf16* wT       = hidB_lo + M_P * 32;   // 67584

    // only the barrier counter needs pre-zeroing
    hipMemsetAsync(ws, 0, 512, stream);

    cp_persist_k<<<NB, 256, 0, stream>>>(
        y, sigma, tau, theta,
        dw1, db1, dw2, db2, dw3, db3,
        pw1, pb1, pw2, pb2, pw3, pb3,
        (float*)d_out, bcnt,
        primal_f, dual_f, pbar1, dual0,
        cat_d_hi, cat_d_lo, cat_p_hi, cat_p_lo,
        hidA_hi, hidA_lo, hidB_hi, hidB_lo, wT);
}

// Round 5
// 3858.949 us; speedup vs baseline: 2.8566x; 1.5867x over previous
//
#include <hip/hip_runtime.h>
#include <math.h>

#define BB 4
#define HHH 128
#define WWW 128
#define AANG 96
#define DDET 128
#define TSTEP 182
#define M_P (BB*HHH*WWW)   // 65536
#define M_D (BB*AANG*DDET) // 49152
#define INV_OPN (1.0f/128.0f)
#define NB 512
#define NT (NB*256)        // 131072 threads
#define NWAVES (NT/64)     // 2048 waves

typedef __bf16 bf16x8 __attribute__((ext_vector_type(8)));
typedef float  f32x4  __attribute__((ext_vector_type(4)));

__device__ __forceinline__ void split_store(__bf16* hi, __bf16* lo, int off, float v) {
    __bf16 h = (__bf16)v;
    hi[off] = h;
    lo[off] = (__bf16)(v - (float)h);
}

// ---- device-scope grid barrier: monotonic counter + per-block private flags ----
// R4 lesson: 511 waves polling ONE line at agent scope => memory-side atomic
// queue convoy (~70us/barrier). Here each block spins on its OWN 64B-spaced
// flag (1 reader/1 writer per line); the last arriver's block fans out the
// generation to all 512 flags (2 coalesced stores/thread).
__device__ __forceinline__ void gbar(unsigned* bcnt, unsigned* flags, unsigned& bar_no) {
    __syncthreads();
    bar_no++;
    __shared__ int is_last_s;
    if (threadIdx.x == 0) {
        __builtin_amdgcn_fence(__ATOMIC_RELEASE, "agent");   // wb dirty lines, once per block
        unsigned prev = __hip_atomic_fetch_add(bcnt, 1u, __ATOMIC_RELAXED, __HIP_MEMORY_SCOPE_AGENT);
        is_last_s = (prev == bar_no * NB - 1u) ? 1 : 0;
    }
    __syncthreads();
    if (is_last_s) {
        for (int i = threadIdx.x; i < NB; i += 256)
            __hip_atomic_store(&flags[i * 16], bar_no, __ATOMIC_RELAXED, __HIP_MEMORY_SCOPE_AGENT);
    } else if (threadIdx.x == 0) {
        while (__hip_atomic_load(&flags[blockIdx.x * 16], __ATOMIC_RELAXED, __HIP_MEMORY_SCOPE_AGENT) < bar_no) {
            __builtin_amdgcn_s_sleep(8);
        }
    }
    __syncthreads();
    __builtin_amdgcn_fence(__ATOMIC_ACQUIRE, "agent");       // invalidate once (compiler orders loads after)
}

// ================= conv core: implicit GEMM, 16x16x32 bf16 MFMA, bf16x3 split =================
template<int CIP, int NCH, int NCOT, int IH>
__device__ __forceinline__ void conv_core(
        const __bf16* __restrict__ Ahi, const __bf16* __restrict__ Alo,
        const __bf16* __restrict__ Whi, const __bf16* __restrict__ Wlo,
        int mtile, f32x4 acc[NCOT])
{
    const int IW = 128;
    const int COP = NCOT * 16;
    int lane = threadIdx.x & 63;
    int n16  = lane & 15;
    int quad = lane >> 4;
    int p0  = mtile * 16;
    int b   = p0 / (IH * IW);
    int rem = p0 - b * (IH * IW);
    int ty  = rem >> 7;
    int tx0 = rem & 127;
    #pragma unroll
    for (int c = 0; c < NCH; ++c) {
        int tap = (CIP == 32) ? c : (c * 4 + quad);
        int dy = tap / 3 - 1;
        int dx = tap % 3 - 1;
        int yy = ty + dy;
        int xx = tx0 + n16 + dx;
        bool valid = (tap < 9) && (yy >= 0) && (yy < IH) && (xx >= 0) && (xx < IW);
        bf16x8 a_h = {};
        bf16x8 a_l = {};
        if (valid) {
            size_t off = (size_t)(b * IH * IW + yy * IW + xx) * CIP
                       + ((CIP == 32) ? (quad * 8) : 0);
            a_h = *(const bf16x8*)(Ahi + off);
            a_l = *(const bf16x8*)(Alo + off);
        }
        #pragma unroll
        for (int ct = 0; ct < NCOT; ++ct) {
            size_t woff = ((size_t)tap * COP + ct * 16 + n16) * CIP
                        + ((CIP == 32) ? (quad * 8) : 0);
            bf16x8 b_h = *(const bf16x8*)(Whi + woff);
            bf16x8 b_l = *(const bf16x8*)(Wlo + woff);
            acc[ct] = __builtin_amdgcn_mfma_f32_16x16x32_bf16(a_h, b_h, acc[ct], 0, 0, 0);
            acc[ct] = __builtin_amdgcn_mfma_f32_16x16x32_bf16(a_h, b_l, acc[ct], 0, 0, 0);
            acc[ct] = __builtin_amdgcn_mfma_f32_16x16x32_bf16(a_l, b_h, acc[ct], 0, 0, 0);
        }
    }
}

__device__ __forceinline__ void epi_ab(const f32x4* acc, const float* __restrict__ bias,
                                       __bf16* Ohi, __bf16* Olo, int mt) {
    int lane = threadIdx.x & 63;
    int n16 = lane & 15;
    int quad = lane >> 4;
    #pragma unroll
    for (int ct = 0; ct < 2; ++ct) {
        float bv = bias[ct * 16 + n16];
        #pragma unroll
        for (int r = 0; r < 4; ++r) {
            float v = fmaxf(acc[ct][r] + bv, 0.f);
            int m = mt * 16 + quad * 4 + r;
            split_store(Ohi, Olo, m * 32 + ct * 16 + n16, v);
        }
    }
}

__global__ __launch_bounds__(256, 2) void cp_persist_k(
    const float* __restrict__ y, const float* __restrict__ sigma,
    const float* __restrict__ tau, const float* __restrict__ theta,
    const float* __restrict__ dw1, const float* __restrict__ db1,
    const float* __restrict__ dw2, const float* __restrict__ db2,
    const float* __restrict__ dw3, const float* __restrict__ db3,
    const float* __restrict__ pw1, const float* __restrict__ pb1,
    const float* __restrict__ pw2, const float* __restrict__ pb2,
    const float* __restrict__ pw3, const float* __restrict__ pb3,
    float* __restrict__ out,
    unsigned* bcnt, unsigned* flags,
    float* primal_f, float* dual_f, float* pbar1, float* dual0,
    __bf16* cat_d_hi, __bf16* cat_d_lo, __bf16* cat_p_hi, __bf16* cat_p_lo,
    __bf16* hidA_hi, __bf16* hidA_lo, __bf16* hidB_hi, __bf16* hidB_lo,
    __bf16* wT)
{
    __shared__ float cs[AANG], ss[AANG];
    const int tid = blockIdx.x * 256 + threadIdx.x;
    const int gw = tid >> 6;
    unsigned bar_no = 0;

    __bf16* d1h = wT;            __bf16* d1l = d1h + 3072;
    __bf16* d2h = d1l + 3072;    __bf16* d2l = d2h + 9216;
    __bf16* d3h = d2l + 9216;    __bf16* d3l = d3h + 4608;
    __bf16* p1h = d3l + 4608;    __bf16* p1l = p1h + 3072;
    __bf16* p2h = p1l + 3072;    __bf16* p2l = p2h + 9216;
    __bf16* p3h = p2l + 9216;    __bf16* p3l = p3h + 4608;

    if (threadIdx.x < AANG) {
        double ang = (double)threadIdx.x * M_PI / (double)AANG;
        cs[threadIdx.x] = (float)cos(ang);
        ss[threadIdx.x] = (float)sin(ang);
    }

    // ---------------- setup: zero state, build cat buffers, transpose/split weights ----------------
    for (int i = tid; i < M_P * 5; i += NT) primal_f[i] = 0.f;
    for (int i = tid; i < M_D * 5; i += NT) dual_f[i] = 0.f;
    for (int i = tid; i < M_P; i += NT) pbar1[i] = 0.f;
    for (int i = tid; i < M_D * 8; i += NT) {
        int ch = i & 7;
        float v = (ch == 6) ? y[i >> 3] : 0.f;
        split_store(cat_d_hi, cat_d_lo, i, v);
    }
    for (int i = tid; i < M_P * 8; i += NT) { cat_p_hi[i] = (__bf16)0.f; cat_p_lo[i] = (__bf16)0.f; }
    for (int i = tid; i < 3072; i += NT) { int tap = i >> 8, co = (i >> 3) & 31, ci = i & 7;
        float v = (tap < 9 && ci < 7) ? dw1[(tap * 7 + ci) * 32 + co] : 0.f; split_store(d1h, d1l, i, v); }
    for (int i = tid; i < 9216; i += NT) { int tap = i >> 10, co = (i >> 5) & 31, ci = i & 31;
        float v = dw2[(tap * 32 + ci) * 32 + co]; split_store(d2h, d2l, i, v); }
    for (int i = tid; i < 4608; i += NT) { int tap = i >> 9, co = (i >> 5) & 15, ci = i & 31;
        float v = (co < 5) ? dw3[(tap * 32 + ci) * 5 + co] : 0.f; split_store(d3h, d3l, i, v); }
    for (int i = tid; i < 3072; i += NT) { int tap = i >> 8, co = (i >> 3) & 31, ci = i & 7;
        float v = (tap < 9 && ci < 6) ? pw1[(tap * 6 + ci) * 32 + co] : 0.f; split_store(p1h, p1l, i, v); }
    for (int i = tid; i < 9216; i += NT) { int tap = i >> 10, co = (i >> 5) & 31, ci = i & 31;
        float v = pw2[(tap * 32 + ci) * 32 + co]; split_store(p2h, p2l, i, v); }
    for (int i = tid; i < 4608; i += NT) { int tap = i >> 9, co = (i >> 5) & 15, ci = i & 31;
        float v = (co < 5) ? pw3[(tap * 32 + ci) * 5 + co] : 0.f; split_store(p3h, p3l, i, v); }

    gbar(bcnt, flags, bar_no);

    const int MT_D = M_D / 16;   // 3072
    const int MT_P = M_P / 16;   // 4096

    for (int it = 0; it < 10; ++it) {
        // ---- S1: radon forward (t-split x2, pair-combine) -> cat_d ch5 ----
        if (tid < 2 * M_D) {
            int pix = tid >> 1, h = tid & 1;
            int d = pix & 127;
            int b = pix / (AANG * DDET);
            int a = (pix - b * AANG * DDET) >> 7;
            float c = cs[a], sn = ss[a];
            float s = (float)d - 63.5f;
            float scx = s * c, ssy = s * sn;
            const float* ib = pbar1 + b * (HHH * WWW);
            float acc = 0.f;
            int t0 = h * 91;
            for (int tt = t0; tt < t0 + 91; ++tt) {
                float t = (float)tt - 90.5f;
                float xi = (scx - t * sn) + 63.5f;
                float yi = (ssy + t * c) + 63.5f;
                float x0f = floorf(xi), y0f = floorf(yi);
                float wx = xi - x0f, wy = yi - y0f;
                int x0 = (int)x0f, y0 = (int)y0f;
                int x1 = x0 + 1, y1 = y0 + 1;
                bool xv0 = (x0 >= 0) & (x0 < WWW);
                bool xv1 = (x1 >= 0) & (x1 < WWW);
                bool yv0 = (y0 >= 0) & (y0 < HHH);
                bool yv1 = (y1 >= 0) & (y1 < HHH);
                float v00 = (yv0 & xv0) ? ib[y0 * WWW + x0] : 0.f;
                float v01 = (yv0 & xv1) ? ib[y0 * WWW + x1] : 0.f;
                float v10 = (yv1 & xv0) ? ib[y1 * WWW + x0] : 0.f;
                float v11 = (yv1 & xv1) ? ib[y1 * WWW + x1] : 0.f;
                acc += v00 * (1.f - wy) * (1.f - wx) + v01 * (1.f - wy) * wx
                     + v10 * wy * (1.f - wx) + v11 * wy * wx;
            }
            float other = __shfl_xor(acc, 1);
            if (h == 0) split_store(cat_d_hi, cat_d_lo, pix * 8 + 5, (acc + other) * INV_OPN);
        }
        gbar(bcnt, flags, bar_no);

        // ---- S2: dual conv1 ----
        for (int mt = gw; mt < MT_D; mt += NWAVES) {
            f32x4 acc[2] = {};
            conv_core<8, 3, 2, AANG>(cat_d_hi, cat_d_lo, d1h, d1l, mt, acc);
            epi_ab(acc, db1, hidA_hi, hidA_lo, mt);
        }
        gbar(bcnt, flags, bar_no);

        // ---- S3: dual conv2 ----
        for (int mt = gw; mt < MT_D; mt += NWAVES) {
            f32x4 acc[2] = {};
            conv_core<32, 9, 2, AANG>(hidA_hi, hidA_lo, d2h, d2l, mt, acc);
            epi_ab(acc, db2, hidB_hi, hidB_lo, mt);
        }
        gbar(bcnt, flags, bar_no);

        // ---- S4: dual conv3 + dual update ----
        {
            float sg = *sigma;
            for (int mt = gw; mt < MT_D; mt += NWAVES) {
                f32x4 acc[1] = {};
                conv_core<32, 9, 1, AANG>(hidB_hi, hidB_lo, d3h, d3l, mt, acc);
                int lane = threadIdx.x & 63;
                int n16 = lane & 15;
                int quad = lane >> 4;
                if (n16 < 5) {
                    float bv = db3[n16];
                    #pragma unroll
                    for (int r = 0; r < 4; ++r) {
                        int m = mt * 16 + quad * 4 + r;
                        float v = acc[0][r] + bv;
                        float dn = dual_f[m * 5 + n16] + sg * v;
                        dual_f[m * 5 + n16] = dn;
                        split_store(cat_d_hi, cat_d_lo, m * 8 + n16, dn);
                        if (n16 == 0) dual0[m] = dn;
                    }
                }
            }
        }
        gbar(bcnt, flags, bar_no);

        // ---- S5: radon adjoint (a-split x2, pair-combine) -> cat_p ch5 ----
        if (tid < 2 * M_P) {
            int pix = tid >> 1, h = tid & 1;
            int x = pix & 127;
            int yv = (pix >> 7) & 127;
            int b = pix >> 14;
            float px = (float)x - 63.5f;
            float py = (float)yv - 63.5f;
            const float* sb = dual0 + b * (AANG * DDET);
            float acc = 0.f;
            int a0 = h * 48;
            for (int a = a0; a < a0 + 48; ++a) {
                float det = px * cs[a] + py * ss[a] + 63.5f;
                float dh = floorf(det);
                float w = det - dh;
                int d0 = (int)dh;
                int d1 = d0 + 1;
                float v0 = (d0 >= 0 && d0 < DDET) ? sb[a * DDET + d0] : 0.f;
                float v1 = (d1 >= 0 && d1 < DDET) ? sb[a * DDET + d1] : 0.f;
                acc += v0 * (1.f - w) + v1 * w;
            }
            float other = __shfl_xor(acc, 1);
            if (h == 0) split_store(cat_p_hi, cat_p_lo, pix * 8 + 5, (acc + other) * INV_OPN);
        }
        gbar(bcnt, flags, bar_no);

        // ---- S6: primal conv1 ----
        for (int mt = gw; mt < MT_P; mt += NWAVES) {
            f32x4 acc[2] = {};
            conv_core<8, 3, 2, HHH>(cat_p_hi, cat_p_lo, p1h, p1l, mt, acc);
            epi_ab(acc, pb1, hidA_hi, hidA_lo, mt);
        }
        gbar(bcnt, flags, bar_no);

        // ---- S7: primal conv2 ----
        for (int mt = gw; mt < MT_P; mt += NWAVES) {
            f32x4 acc[2] = {};
            conv_core<32, 9, 2, HHH>(hidA_hi, hidA_lo, p2h, p2l, mt, acc);
            epi_ab(acc, pb2, hidB_hi, hidB_lo, mt);
        }
        gbar(bcnt, flags, bar_no);

        // ---- S8: primal conv3 + primal/primal_bar update ----
        {
            float ta = *tau;
            float th = *theta;
            for (int mt = gw; mt < MT_P; mt += NWAVES) {
                f32x4 acc[1] = {};
                conv_core<32, 9, 1, HHH>(hidB_hi, hidB_lo, p3h, p3l, mt, acc);
                int lane = threadIdx.x & 63;
                int n16 = lane & 15;
                int quad = lane >> 4;
                if (n16 < 5) {
                    float bv = pb3[n16];
                    #pragma unroll
                    for (int r = 0; r < 4; ++r) {
                        int m = mt * 16 + quad * 4 + r;
                        float v = acc[0][r] + bv;
                        float pold = primal_f[m * 5 + n16];
                        float pn = pold + ta * v;
                        primal_f[m * 5 + n16] = pn;
                        split_store(cat_p_hi, cat_p_lo, m * 8 + n16, pn);
                        if (n16 == 1) pbar1[m] = pn + th * (pn - pold);
                    }
                }
            }
        }
        gbar(bcnt, flags, bar_no);
    }

    // ---- extract ch0 ----
    if (tid < M_P) out[tid] = primal_f[tid * 5];
}

extern "C" void kernel_launch(void* const* d_in, const int* in_sizes, int n_in,
                              void* d_out, int out_size, void* d_ws, size_t ws_size,
                              hipStream_t stream) {
    const float* y     = (const float*)d_in[0];
    const float* sigma = (const float*)d_in[1];
    const float* tau   = (const float*)d_in[2];
    const float* theta = (const float*)d_in[3];
    const float* dw1 = (const float*)d_in[4];
    const float* db1 = (const float*)d_in[5];
    const float* dw2 = (const float*)d_in[6];
    const float* db2 = (const float*)d_in[7];
    const float* dw3 = (const float*)d_in[8];
    const float* db3 = (const float*)d_in[9];
    const float* pw1 = (const float*)d_in[10];
    const float* pb1 = (const float*)d_in[11];
    const float* pw2 = (const float*)d_in[12];
    const float* pb2 = (const float*)d_in[13];
    const float* pw3 = (const float*)d_in[14];
    const float* pb3 = (const float*)d_in[15];

    float* ws = (float*)d_ws;
    unsigned* bcnt  = (unsigned*)ws;          // barrier counter (own line)
    unsigned* flags = (unsigned*)(ws + 128);  // NB flags, 64B apart = 32KB
    float* primal_f = ws + 128 + NB * 16;     // M_P*5
    float* dual_f   = primal_f + M_P * 5;     // M_D*5
    float* pbar1    = dual_f + M_D * 5;       // M_P
    float* dual0    = pbar1 + M_P;            // M_D
    __bf16* bf = (__bf16*)(dual0 + M_D);
    __bf16* cat_d_hi = bf;                    // M_D*8
    __bf16* cat_d_lo = cat_d_hi + M_D * 8;
    __bf16* cat_p_hi = cat_d_lo + M_D * 8;    // M_P*8
    __bf16* cat_p_lo = cat_p_hi + M_P * 8;
    __bf16* hidA_hi  = cat_p_lo + M_P * 8;    // M_P*32
    __bf16* hidA_lo  = hidA_hi + M_P * 32;
    __bf16* hidB_hi  = hidA_lo + M_P * 32;
    __bf16* hidB_lo  = hidB_hi + M_P * 32;
    __bf16* wT       = hidB_lo + M_P * 32;    // 67584

    // zero barrier counter + flags
    hipMemsetAsync(ws, 0, (128 + NB * 16) * sizeof(float) / 1 , stream);

    cp_persist_k<<<NB, 256, 0, stream>>>(
        y, sigma, tau, theta,
        dw1, db1, dw2, db2, dw3, db3,
        pw1, pb1, pw2, pb2, pw3, pb3,
        (float*)d_out, bcnt, flags,
        primal_f, dual_f, pbar1, dual0,
        cat_d_hi, cat_d_lo, cat_p_hi, cat_p_lo,
        hidA_hi, hidA_lo, hidB_hi, hidB_lo, wT);
}

// Round 6
// 2722.545 us; speedup vs baseline: 4.0490x; 1.4174x over previous
//
#include <hip/hip_runtime.h>
#include <math.h>

#define BB 4
#define HHH 128
#define WWW 128
#define AANG 96
#define DDET 128
#define TSTEP 182
#define M_P (BB*HHH*WWW)   // 65536
#define M_D (BB*AANG*DDET) // 49152
#define INV_OPN (1.0f/128.0f)
#define NB 512
#define NT (NB*256)        // 131072 threads
#define NWAVES (NT/64)     // 2048 waves

typedef __bf16 bf16x8 __attribute__((ext_vector_type(8)));
typedef short  short8 __attribute__((ext_vector_type(8)));
typedef float  f32x4  __attribute__((ext_vector_type(4)));
typedef unsigned int uint;

// ---------- device-coherent (sc0 sc1, L1/L2-bypass) accessors ----------
// Relaxed agent-scope atomics compile to global_load/store with coherence
// bits set: they read/write the memory-side coherence point directly, so
// cross-XCD visibility needs NO buffer_inv/wbl2 fences. The compiler tracks
// vmcnt for them (many in flight, one drain before use).
__device__ __forceinline__ unsigned long long cload_u64(const uint* p) {
    return __hip_atomic_load((const unsigned long long*)p, __ATOMIC_RELAXED, __HIP_MEMORY_SCOPE_AGENT);
}
__device__ __forceinline__ float cload_f(const float* p) {
    return __hip_atomic_load(p, __ATOMIC_RELAXED, __HIP_MEMORY_SCOPE_AGENT);
}
__device__ __forceinline__ void cstore_f(float* p, float v) {
    __hip_atomic_store(p, v, __ATOMIC_RELAXED, __HIP_MEMORY_SCOPE_AGENT);
}

// packed bf16 hi/lo pair (bf16x3-split activation element) in one 4B word
__device__ __forceinline__ uint pack_pair(float v) {
    union { __bf16 b; unsigned short s; } ch, cl;
    ch.b = (__bf16)v;
    cl.b = (__bf16)(v - (float)ch.b);
    return (uint)ch.s | ((uint)cl.s << 16);
}
__device__ __forceinline__ void cstore_pair(uint* p, float v) {
    __hip_atomic_store(p, pack_pair(v), __ATOMIC_RELAXED, __HIP_MEMORY_SCOPE_AGENT);
}

union BS { short8 s; bf16x8 b; unsigned long long u[2]; };

// ---- grid barrier: monotonic counter + per-block private flags ----
// MODE: 0 = plain (no cache maintenance), 1 = L2-invalidate after (for
// stages doing CACHED reads of sc-written data), 2 = full release+inv (setup)
template<int MODE>
__device__ __forceinline__ void gbar(uint* bcnt, uint* flags, uint& bar_no) {
    __syncthreads();   // compiler drains vmcnt(0) before s_barrier => all block stores visible
    bar_no++;
    __shared__ int is_last_s;
    if (threadIdx.x == 0) {
        if (MODE == 2) __builtin_amdgcn_fence(__ATOMIC_RELEASE, "agent");  // wbl2 once (setup)
        uint prev = __hip_atomic_fetch_add(bcnt, 1u, __ATOMIC_RELAXED, __HIP_MEMORY_SCOPE_AGENT);
        is_last_s = (prev == bar_no * NB - 1u) ? 1 : 0;
    }
    __syncthreads();
    if (is_last_s) {
        for (int i = threadIdx.x; i < NB; i += 256)
            __hip_atomic_store(&flags[i * 16], bar_no, __ATOMIC_RELAXED, __HIP_MEMORY_SCOPE_AGENT);
    } else if (threadIdx.x == 0) {
        while (__hip_atomic_load(&flags[blockIdx.x * 16], __ATOMIC_RELAXED, __HIP_MEMORY_SCOPE_AGENT) < bar_no)
            __builtin_amdgcn_s_sleep(8);
    }
    __syncthreads();
    if (MODE >= 1) __builtin_amdgcn_fence(__ATOMIC_ACQUIRE, "agent");      // buffer_inv (2x/iter only)
    else           __builtin_amdgcn_fence(__ATOMIC_ACQUIRE, "workgroup");  // compiler barrier, cheap
}

// ===== conv core: implicit GEMM, 16x16x32 bf16 MFMA, bf16x3 split =====
// A: packed-pair activations [pix][CIP] (uint = hi|lo<<16), coherent loads
// W: separate hi/lo [tap][COP][CIP] bf16, NORMAL cached loads (L2-warm)
template<int CIP, int NCH, int NCOT, int IH>
__device__ __forceinline__ void conv_core(
        const uint* __restrict__ A,
        const __bf16* __restrict__ Whi, const __bf16* __restrict__ Wlo,
        int mtile, f32x4 acc[NCOT])
{
    const int IW = 128;
    const int COP = NCOT * 16;
    int lane = threadIdx.x & 63;
    int n16  = lane & 15;
    int quad = lane >> 4;
    int p0  = mtile * 16;
    int b   = p0 / (IH * IW);
    int rem = p0 - b * (IH * IW);
    int ty  = rem >> 7;
    int tx0 = rem & 127;
    #pragma unroll
    for (int c = 0; c < NCH; ++c) {
        int tap = (CIP == 32) ? c : (c * 4 + quad);
        int dy = tap / 3 - 1;
        int dx = tap % 3 - 1;
        int yy = ty + dy;
        int xx = tx0 + n16 + dx;
        bool valid = (tap < 9) && (yy >= 0) && (yy < IH) && (xx >= 0) && (xx < IW);
        BS v0, v1;
        v0.u[0] = 0; v0.u[1] = 0; v1.u[0] = 0; v1.u[1] = 0;
        if (valid) {
            const uint* p = A + ((size_t)(b * IH * IW + yy * IW + xx) * CIP
                                 + ((CIP == 32) ? (quad * 8) : 0));
            v0.u[0] = cload_u64(p);     v0.u[1] = cload_u64(p + 2);
            v1.u[0] = cload_u64(p + 4); v1.u[1] = cload_u64(p + 6);
        }
        BS hs, ls;
        hs.s = __builtin_shufflevector(v0.s, v1.s, 0, 2, 4, 6, 8, 10, 12, 14);
        ls.s = __builtin_shufflevector(v0.s, v1.s, 1, 3, 5, 7, 9, 11, 13, 15);
        #pragma unroll
        for (int ct = 0; ct < NCOT; ++ct) {
            size_t woff = ((size_t)tap * COP + ct * 16 + n16) * CIP
                        + ((CIP == 32) ? (quad * 8) : 0);
            bf16x8 b_h = *(const bf16x8*)(Whi + woff);
            bf16x8 b_l = *(const bf16x8*)(Wlo + woff);
            acc[ct] = __builtin_amdgcn_mfma_f32_16x16x32_bf16(hs.b, b_h, acc[ct], 0, 0, 0);
            acc[ct] = __builtin_amdgcn_mfma_f32_16x16x32_bf16(hs.b, b_l, acc[ct], 0, 0, 0);
            acc[ct] = __builtin_amdgcn_mfma_f32_16x16x32_bf16(ls.b, b_h, acc[ct], 0, 0, 0);
        }
    }
}

__device__ __forceinline__ void epi_ab(const f32x4* acc, const float* __restrict__ bias,
                                       uint* O, int mt) {
    int lane = threadIdx.x & 63;
    int n16 = lane & 15;
    int quad = lane >> 4;
    #pragma unroll
    for (int ct = 0; ct < 2; ++ct) {
        float bv = bias[ct * 16 + n16];
        #pragma unroll
        for (int r = 0; r < 4; ++r) {
            float v = fmaxf(acc[ct][r] + bv, 0.f);
            int m = mt * 16 + quad * 4 + r;
            cstore_pair(O + (m * 32 + ct * 16 + n16), v);
        }
    }
}

__global__ __launch_bounds__(256, 2) void cp_persist_k(
    const float* __restrict__ y, const float* __restrict__ sigma,
    const float* __restrict__ tau, const float* __restrict__ theta,
    const float* __restrict__ dw1, const float* __restrict__ db1,
    const float* __restrict__ dw2, const float* __restrict__ db2,
    const float* __restrict__ dw3, const float* __restrict__ db3,
    const float* __restrict__ pw1, const float* __restrict__ pb1,
    const float* __restrict__ pw2, const float* __restrict__ pb2,
    const float* __restrict__ pw3, const float* __restrict__ pb3,
    float* __restrict__ out,
    uint* bcnt, uint* flags,
    float* primal_f, float* dual_f, float* pbar1, float* dual0,
    uint* catD, uint* catP, uint* hidA, uint* hidB,
    __bf16* wT)
{
    __shared__ float cs[AANG], ss[AANG];
    const int tid = blockIdx.x * 256 + threadIdx.x;
    const int gw = tid >> 6;
    uint bar_no = 0;

    __bf16* d1h = wT;            __bf16* d1l = d1h + 3072;
    __bf16* d2h = d1l + 3072;    __bf16* d2l = d2h + 9216;
    __bf16* d3h = d2l + 9216;    __bf16* d3l = d3h + 4608;
    __bf16* p1h = d3l + 4608;    __bf16* p1l = p1h + 3072;
    __bf16* p2h = p1l + 3072;    __bf16* p2l = p2h + 9216;
    __bf16* p3h = p2l + 9216;    __bf16* p3l = p3h + 4608;

    if (threadIdx.x < AANG) {
        double ang = (double)threadIdx.x * M_PI / (double)AANG;
        cs[threadIdx.x] = (float)cos(ang);
        ss[threadIdx.x] = (float)sin(ang);
    }

    // ---------------- setup (plain stores; flushed by the MODE-2 barrier) ----------------
    for (int i = tid; i < M_P * 5; i += NT) primal_f[i] = 0.f;
    for (int i = tid; i < M_D * 5; i += NT) dual_f[i] = 0.f;
    for (int i = tid; i < M_P; i += NT) pbar1[i] = 0.f;
    for (int i = tid; i < M_D * 8; i += NT) {
        int ch = i & 7;
        catD[i] = (ch == 6) ? pack_pair(y[i >> 3]) : 0u;
    }
    for (int i = tid; i < M_P * 8; i += NT) catP[i] = 0u;
    {
        union { __bf16 b; unsigned short s; } cv;
        for (int i = tid; i < 3072; i += NT) { int tap = i >> 8, co = (i >> 3) & 31, ci = i & 7;
            float v = (tap < 9 && ci < 7) ? dw1[(tap * 7 + ci) * 32 + co] : 0.f;
            cv.b = (__bf16)v; d1h[i] = cv.b; d1l[i] = (__bf16)(v - (float)cv.b); }
        for (int i = tid; i < 9216; i += NT) { int tap = i >> 10, co = (i >> 5) & 31, ci = i & 31;
            float v = dw2[(tap * 32 + ci) * 32 + co];
            cv.b = (__bf16)v; d2h[i] = cv.b; d2l[i] = (__bf16)(v - (float)cv.b); }
        for (int i = tid; i < 4608; i += NT) { int tap = i >> 9, co = (i >> 5) & 15, ci = i & 31;
            float v = (co < 5) ? dw3[(tap * 32 + ci) * 5 + co] : 0.f;
            cv.b = (__bf16)v; d3h[i] = cv.b; d3l[i] = (__bf16)(v - (float)cv.b); }
        for (int i = tid; i < 3072; i += NT) { int tap = i >> 8, co = (i >> 3) & 31, ci = i & 7;
            float v = (tap < 9 && ci < 6) ? pw1[(tap * 6 + ci) * 32 + co] : 0.f;
            cv.b = (__bf16)v; p1h[i] = cv.b; p1l[i] = (__bf16)(v - (float)cv.b); }
        for (int i = tid; i < 9216; i += NT) { int tap = i >> 10, co = (i >> 5) & 31, ci = i & 31;
            float v = pw2[(tap * 32 + ci) * 32 + co];
            cv.b = (__bf16)v; p2h[i] = cv.b; p2l[i] = (__bf16)(v - (float)cv.b); }
        for (int i = tid; i < 4608; i += NT) { int tap = i >> 9, co = (i >> 5) & 15, ci = i & 31;
            float v = (co < 5) ? pw3[(tap * 32 + ci) * 5 + co] : 0.f;
            cv.b = (__bf16)v; p3h[i] = cv.b; p3l[i] = (__bf16)(v - (float)cv.b); }
    }

    gbar<2>(bcnt, flags, bar_no);   // full fence: setup data -> L3, caches clean

    const int MT_D = M_D / 16;   // 3072
    const int MT_P = M_P / 16;   // 4096

    for (int it = 0; it < 10; ++it) {
        // ---- S1: radon forward (CACHED reads of pbar1; INV'd at prev barrier) ----
        if (tid < 2 * M_D) {
            int pix = tid >> 1, h = tid & 1;
            int d = pix & 127;
            int b = pix / (AANG * DDET);
            int a = (pix - b * AANG * DDET) >> 7;
            float c = cs[a], sn = ss[a];
            float s = (float)d - 63.5f;
            float scx = s * c, ssy = s * sn;
            const float* ib = pbar1 + b * (HHH * WWW);
            float acc = 0.f;
            int t0 = h * 91;
            for (int tt = t0; tt < t0 + 91; ++tt) {
                float t = (float)tt - 90.5f;
                float xi = (scx - t * sn) + 63.5f;
                float yi = (ssy + t * c) + 63.5f;
                float x0f = floorf(xi), y0f = floorf(yi);
                float wx = xi - x0f, wy = yi - y0f;
                int x0 = (int)x0f, y0 = (int)y0f;
                int x1 = x0 + 1, y1 = y0 + 1;
                bool xv0 = (x0 >= 0) & (x0 < WWW);
                bool xv1 = (x1 >= 0) & (x1 < WWW);
                bool yv0 = (y0 >= 0) & (y0 < HHH);
                bool yv1 = (y1 >= 0) & (y1 < HHH);
                float v00 = (yv0 & xv0) ? ib[y0 * WWW + x0] : 0.f;
                float v01 = (yv0 & xv1) ? ib[y0 * WWW + x1] : 0.f;
                float v10 = (yv1 & xv0) ? ib[y1 * WWW + x0] : 0.f;
                float v11 = (yv1 & xv1) ? ib[y1 * WWW + x1] : 0.f;
                acc += v00 * (1.f - wy) * (1.f - wx) + v01 * (1.f - wy) * wx
                     + v10 * wy * (1.f - wx) + v11 * wy * wx;
            }
            float other = __shfl_xor(acc, 1);
            if (h == 0) cstore_pair(catD + (pix * 8 + 5), (acc + other) * INV_OPN);
        }
        gbar<0>(bcnt, flags, bar_no);

        // ---- S2: dual conv1 ----
        for (int mt = gw; mt < MT_D; mt += NWAVES) {
            f32x4 acc[2] = {};
            conv_core<8, 3, 2, AANG>(catD, d1h, d1l, mt, acc);
            epi_ab(acc, db1, hidA, mt);
        }
        gbar<0>(bcnt, flags, bar_no);

        // ---- S3: dual conv2 ----
        for (int mt = gw; mt < MT_D; mt += NWAVES) {
            f32x4 acc[2] = {};
            conv_core<32, 9, 2, AANG>(hidA, d2h, d2l, mt, acc);
            epi_ab(acc, db2, hidB, mt);
        }
        gbar<0>(bcnt, flags, bar_no);

        // ---- S4: dual conv3 + dual update ----
        {
            float sg = *sigma;
            for (int mt = gw; mt < MT_D; mt += NWAVES) {
                f32x4 acc[1] = {};
                conv_core<32, 9, 1, AANG>(hidB, d3h, d3l, mt, acc);
                int lane = threadIdx.x & 63;
                int n16 = lane & 15;
                int quad = lane >> 4;
                if (n16 < 5) {
                    float bv = db3[n16];
                    #pragma unroll
                    for (int r = 0; r < 4; ++r) {
                        int m = mt * 16 + quad * 4 + r;
                        float v = acc[0][r] + bv;
                        float dn = cload_f(&dual_f[m * 5 + n16]) + sg * v;
                        cstore_f(&dual_f[m * 5 + n16], dn);
                        cstore_pair(catD + (m * 8 + n16), dn);
                        if (n16 == 0) cstore_f(&dual0[m], dn);
                    }
                }
            }
        }
        gbar<1>(bcnt, flags, bar_no);   // INV: S5 does cached reads of dual0

        // ---- S5: radon adjoint (CACHED reads of dual0) ----
        if (tid < 2 * M_P) {
            int pix = tid >> 1, h = tid & 1;
            int x = pix & 127;
            int yv = (pix >> 7) & 127;
            int b = pix >> 14;
            float px = (float)x - 63.5f;
            float py = (float)yv - 63.5f;
            const float* sb = dual0 + b * (AANG * DDET);
            float acc = 0.f;
            int a0 = h * 48;
            for (int a = a0; a < a0 + 48; ++a) {
                float det = px * cs[a] + py * ss[a] + 63.5f;
                float dh = floorf(det);
                float w = det - dh;
                int d0 = (int)dh;
                int d1 = d0 + 1;
                float v0 = (d0 >= 0 && d0 < DDET) ? sb[a * DDET + d0] : 0.f;
                float v1 = (d1 >= 0 && d1 < DDET) ? sb[a * DDET + d1] : 0.f;
                acc += v0 * (1.f - w) + v1 * w;
            }
            float other = __shfl_xor(acc, 1);
            if (h == 0) cstore_pair(catP + (pix * 8 + 5), (acc + other) * INV_OPN);
        }
        gbar<0>(bcnt, flags, bar_no);

        // ---- S6: primal conv1 ----
        for (int mt = gw; mt < MT_P; mt += NWAVES) {
            f32x4 acc[2] = {};
            conv_core<8, 3, 2, HHH>(catP, p1h, p1l, mt, acc);
            epi_ab(acc, pb1, hidA, mt);
        }
        gbar<0>(bcnt, flags, bar_no);

        // ---- S7: primal conv2 ----
        for (int mt = gw; mt < MT_P; mt += NWAVES) {
            f32x4 acc[2] = {};
            conv_core<32, 9, 2, HHH>(hidA, p2h, p2l, mt, acc);
            epi_ab(acc, pb2, hidB, mt);
        }
        gbar<0>(bcnt, flags, bar_no);

        // ---- S8: primal conv3 + primal/primal_bar update ----
        {
            float ta = *tau;
            float th = *theta;
            for (int mt = gw; mt < MT_P; mt += NWAVES) {
                f32x4 acc[1] = {};
                conv_core<32, 9, 1, HHH>(hidB, p3h, p3l, mt, acc);
                int lane = threadIdx.x & 63;
                int n16 = lane & 15;
                int quad = lane >> 4;
                if (n16 < 5) {
                    float bv = pb3[n16];
                    #pragma unroll
                    for (int r = 0; r < 4; ++r) {
                        int m = mt * 16 + quad * 4 + r;
                        float v = acc[0][r] + bv;
                        float pold = cload_f(&primal_f[m * 5 + n16]);
                        float pn = pold + ta * v;
                        cstore_f(&primal_f[m * 5 + n16], pn);
                        cstore_pair(catP + (m * 8 + n16), pn);
                        if (n16 == 1) cstore_f(&pbar1[m], pn + th * (pn - pold));
                    }
                }
            }
        }
        gbar<1>(bcnt, flags, bar_no);   // INV: S1 (next iter) does cached reads of pbar1
    }

    // ---- extract ch0 (coherent reads; primal_f is sc-mode) ----
    if (tid < M_P) out[tid] = cload_f(&primal_f[tid * 5]);
}

extern "C" void kernel_launch(void* const* d_in, const int* in_sizes, int n_in,
                              void* d_out, int out_size, void* d_ws, size_t ws_size,
                              hipStream_t stream) {
    const float* y     = (const float*)d_in[0];
    const float* sigma = (const float*)d_in[1];
    const float* tau   = (const float*)d_in[2];
    const float* theta = (const float*)d_in[3];
    const float* dw1 = (const float*)d_in[4];
    const float* db1 = (const float*)d_in[5];
    const float* dw2 = (const float*)d_in[6];
    const float* db2 = (const float*)d_in[7];
    const float* dw3 = (const float*)d_in[8];
    const float* db3 = (const float*)d_in[9];
    const float* pw1 = (const float*)d_in[10];
    const float* pb1 = (const float*)d_in[11];
    const float* pw2 = (const float*)d_in[12];
    const float* pb2 = (const float*)d_in[13];
    const float* pw3 = (const float*)d_in[14];
    const float* pb3 = (const float*)d_in[15];

    float* ws = (float*)d_ws;
    uint* bcnt  = (uint*)ws;
    uint* flags = (uint*)(ws + 128);          // NB flags, 64B apart
    float* primal_f = ws + 128 + NB * 16;     // M_P*5
    float* dual_f   = primal_f + M_P * 5;     // M_D*5
    float* pbar1    = dual_f + M_D * 5;       // M_P
    float* dual0    = pbar1 + M_P;            // M_D
    uint* catD = (uint*)(dual0 + M_D);        // M_D*8 packed pairs
    uint* catP = catD + M_D * 8;              // M_P*8
    uint* hidA = catP + M_P * 8;              // M_P*32
    uint* hidB = hidA + M_P * 32;             // M_P*32
    __bf16* wT = (__bf16*)(hidB + M_P * 32);  // 67584 bf16

    hipMemsetAsync(ws, 0, (size_t)(128 + NB * 16) * 4, stream);

    cp_persist_k<<<NB, 256, 0, stream>>>(
        y, sigma, tau, theta,
        dw1, db1, dw2, db2, dw3, db3,
        pw1, pb1, pw2, pb2, pw3, pb3,
        (float*)d_out, bcnt, flags,
        primal_f, dual_f, pbar1, dual0,
        catD, catP, hidA, hidB, wT);
}

// Round 7
// 2679.564 us; speedup vs baseline: 4.1139x; 1.0160x over previous
//
#include <hip/hip_runtime.h>
#include <math.h>

#define BB 4
#define HHH 128
#define WWW 128
#define AANG 96
#define DDET 128
#define TSTEP 182
#define M_P (BB*HHH*WWW)   // 65536
#define M_D (BB*AANG*DDET) // 49152
#define INV_OPN (1.0f/128.0f)
#define NB 512
#define NT (NB*256)        // 131072 threads

typedef __bf16 bf16x8 __attribute__((ext_vector_type(8)));
typedef short  short8 __attribute__((ext_vector_type(8)));
typedef float  f32x4  __attribute__((ext_vector_type(4)));
typedef unsigned int uint;
typedef unsigned long long u64;

// ---------- device-coherent (sc0 sc1) accessors ----------
__device__ __forceinline__ u64 cload_u64(const uint* p) {
    return __hip_atomic_load((const u64*)p, __ATOMIC_RELAXED, __HIP_MEMORY_SCOPE_AGENT);
}
__device__ __forceinline__ float cload_f(const float* p) {
    return __hip_atomic_load(p, __ATOMIC_RELAXED, __HIP_MEMORY_SCOPE_AGENT);
}
__device__ __forceinline__ void cstore_f(float* p, float v) {
    __hip_atomic_store(p, v, __ATOMIC_RELAXED, __HIP_MEMORY_SCOPE_AGENT);
}
__device__ __forceinline__ uint pack_pair(float v) {
    union { __bf16 b; unsigned short s; } ch, cl;
    ch.b = (__bf16)v;
    cl.b = (__bf16)(v - (float)ch.b);
    return (uint)ch.s | ((uint)cl.s << 16);
}
__device__ __forceinline__ void cstore_pair(uint* p, float v) {
    __hip_atomic_store(p, pack_pair(v), __ATOMIC_RELAXED, __HIP_MEMORY_SCOPE_AGENT);
}

union BS { short8 s; bf16x8 b; u64 u[2]; };

__device__ __forceinline__ void lds_frag(const uint* base, BS& hs, BS& ls) {
    const u64* p = (const u64*)base;
    BS v0, v1;
    v0.u[0] = p[0]; v0.u[1] = p[1]; v1.u[0] = p[2]; v1.u[1] = p[3];
    hs.s = __builtin_shufflevector(v0.s, v1.s, 0, 2, 4, 6, 8, 10, 12, 14);
    ls.s = __builtin_shufflevector(v0.s, v1.s, 1, 3, 5, 7, 9, 11, 13, 15);
}

// ---- grid barrier: monotonic counter + per-block private flags ----
// MODE: 0 = plain, 1 = L2-invalidate after (stage does cached reads of
// sc-written data), 2 = full release+inv (setup)
template<int MODE>
__device__ __forceinline__ void gbar(uint* bcnt, uint* flags, uint& bar_no) {
    __syncthreads();
    bar_no++;
    __shared__ int is_last_s;
    if (threadIdx.x == 0) {
        if (MODE == 2) __builtin_amdgcn_fence(__ATOMIC_RELEASE, "agent");
        uint prev = __hip_atomic_fetch_add(bcnt, 1u, __ATOMIC_RELAXED, __HIP_MEMORY_SCOPE_AGENT);
        is_last_s = (prev == bar_no * NB - 1u) ? 1 : 0;
    }
    __syncthreads();
    if (is_last_s) {
        for (int i = threadIdx.x; i < NB; i += 256)
            __hip_atomic_store(&flags[i * 16], bar_no, __ATOMIC_RELAXED, __HIP_MEMORY_SCOPE_AGENT);
    } else if (threadIdx.x == 0) {
        while (__hip_atomic_load(&flags[blockIdx.x * 16], __ATOMIC_RELAXED, __HIP_MEMORY_SCOPE_AGENT) < bar_no)
            __builtin_amdgcn_s_sleep(8);
    }
    __syncthreads();
    if (MODE >= 1) __builtin_amdgcn_fence(__ATOMIC_ACQUIRE, "agent");
    else           __builtin_amdgcn_fence(__ATOMIC_ACQUIRE, "workgroup");
}

#define MFMA(a,b,c) __builtin_amdgcn_mfma_f32_16x16x32_bf16((a),(b),(c),0,0,0)

// ===== fused conv chain: stage cat(18x18x8) -> conv1 -> hid1(16x16x32 LDS)
//       -> conv2 -> hid2(14x14x32 LDS) -> conv3 -> acc3 (3 tiles/wave) =====
// lds layout: hid1 = lds[0..9216), aux = lds[9216..17280) (cat then hid2)
template<int IH>
__device__ void chain_convs(
        const uint* __restrict__ catG,
        const __bf16* w1h, const __bf16* w1l,
        const __bf16* w2h, const __bf16* w2l,
        const __bf16* w3h, const __bf16* w3l,
        const float* __restrict__ b1, const float* __restrict__ b2,
        uint* lds, int b, int ty0, int tx0, f32x4 acc3[3])
{
    uint* hid1 = lds;
    uint* aux  = lds + 9216;
    const int lane = threadIdx.x & 63;
    const int n16  = lane & 15;
    const int quad = lane >> 4;
    const int wv   = threadIdx.x >> 6;

    // ---- stage cat tile (coherent) + zero hid1 ----
    for (int idx = threadIdx.x; idx < 1296; idx += 256) {
        int pixloc = idx >> 2, part = idx & 3;
        int ly = pixloc / 18, lx = pixloc - ly * 18;
        int gy = ty0 - 3 + ly, gx = tx0 - 3 + lx;
        u64 v = 0;
        if (gy >= 0 && gy < IH && gx >= 0 && gx < 128)
            v = cload_u64(catG + ((size_t)(b * IH * 128 + gy * 128 + gx) * 8 + part * 2));
        *(u64*)(aux + pixloc * 8 + part * 2) = v;
    }
    for (int i = threadIdx.x; i < 9216; i += 256) hid1[i] = 0;
    __syncthreads();

    // ---- conv1: cat(CIP=8) -> hid1, relu ----
    for (int k = 0; k < 4; ++k) {
        int Py = wv, Px = k;
        int i = Py * 4 + (n16 >> 2), j = Px * 4 + (n16 & 3);
        f32x4 acc[2] = {};
        #pragma unroll
        for (int c = 0; c < 3; ++c) {
            int tap = c * 4 + quad;
            BS hs, ls;
            if (tap < 9) {
                int dy = tap / 3 - 1, dx = tap % 3 - 1;
                lds_frag(aux + ((i + 1 + dy) * 18 + (j + 1 + dx)) * 8, hs, ls);
            } else { hs.u[0] = hs.u[1] = ls.u[0] = ls.u[1] = 0; }
            #pragma unroll
            for (int ct = 0; ct < 2; ++ct) {
                size_t woff = ((size_t)tap * 32 + ct * 16 + n16) * 8;
                bf16x8 bh = *(const bf16x8*)(w1h + woff);
                bf16x8 bl = *(const bf16x8*)(w1l + woff);
                acc[ct] = MFMA(hs.b, bh, acc[ct]);
                acc[ct] = MFMA(hs.b, bl, acc[ct]);
                acc[ct] = MFMA(ls.b, bh, acc[ct]);
            }
        }
        int i2 = Py * 4 + quad;
        int gy = ty0 - 2 + i2;
        #pragma unroll
        for (int ct = 0; ct < 2; ++ct) {
            float bv = b1[ct * 16 + n16];
            #pragma unroll
            for (int r = 0; r < 4; ++r) {
                int j2 = Px * 4 + r;
                int gx = tx0 - 2 + j2;
                if (gy >= 0 && gy < IH && gx >= 0 && gx < 128) {
                    float v = fmaxf(acc[ct][r] + bv, 0.f);
                    hid1[(i2 * 16 + j2) * 36 + ct * 16 + n16] = pack_pair(v);
                }
            }
        }
    }
    __syncthreads();
    // ---- zero hid2 (overlays cat) ----
    for (int i = threadIdx.x; i < 8064; i += 256) aux[i] = 0;
    __syncthreads();

    // ---- conv2: hid1(CIP=32) -> hid2, relu ----
    for (int k = 0; k < 4; ++k) {
        int Py = wv, Px = k;
        int i = Py * 4 + (n16 >> 2), j = Px * 4 + (n16 & 3);
        f32x4 acc[2] = {};
        #pragma unroll
        for (int tap = 0; tap < 9; ++tap) {
            int dy = tap / 3 - 1, dx = tap % 3 - 1;
            int ry = i + 1 + dy, rx = j + 1 + dx;
            BS hs, ls;
            if (ry < 16 && rx < 16) lds_frag(hid1 + (ry * 16 + rx) * 36 + quad * 8, hs, ls);
            else { hs.u[0] = hs.u[1] = ls.u[0] = ls.u[1] = 0; }
            #pragma unroll
            for (int ct = 0; ct < 2; ++ct) {
                size_t woff = ((size_t)tap * 32 + ct * 16 + n16) * 32 + quad * 8;
                bf16x8 bh = *(const bf16x8*)(w2h + woff);
                bf16x8 bl = *(const bf16x8*)(w2l + woff);
                acc[ct] = MFMA(hs.b, bh, acc[ct]);
                acc[ct] = MFMA(hs.b, bl, acc[ct]);
                acc[ct] = MFMA(ls.b, bh, acc[ct]);
            }
        }
        int i2 = Py * 4 + quad;
        int gy = ty0 - 1 + i2;
        #pragma unroll
        for (int ct = 0; ct < 2; ++ct) {
            float bv = b2[ct * 16 + n16];
            #pragma unroll
            for (int r = 0; r < 4; ++r) {
                int j2 = Px * 4 + r;
                int gx = tx0 - 1 + j2;
                if (i2 < 14 && j2 < 14 && gy >= 0 && gy < IH && gx >= 0 && gx < 128) {
                    float v = fmaxf(acc[ct][r] + bv, 0.f);
                    aux[(i2 * 16 + j2) * 36 + ct * 16 + n16] = pack_pair(v);
                }
            }
        }
    }
    __syncthreads();

    // ---- conv3: hid2(CIP=32) -> acc3 (tiles wv, wv+4, wv+8 over 3x3 grid) ----
    #pragma unroll
    for (int k = 0; k < 3; ++k) {
        f32x4 a = {};
        int t = wv + 4 * k;
        if (t < 9) {
            int Py = t / 3, Px = t - Py * 3;
            int i = Py * 4 + (n16 >> 2), j = Px * 4 + (n16 & 3);
            #pragma unroll
            for (int tap = 0; tap < 9; ++tap) {
                int dy = tap / 3 - 1, dx = tap % 3 - 1;
                int ry = i + 1 + dy, rx = j + 1 + dx;
                BS hs, ls;
                lds_frag(aux + (ry * 16 + rx) * 36 + quad * 8, hs, ls);
                size_t woff = ((size_t)tap * 16 + n16) * 32 + quad * 8;
                bf16x8 bh = *(const bf16x8*)(w3h + woff);
                bf16x8 bl = *(const bf16x8*)(w3l + woff);
                a = MFMA(hs.b, bh, a);
                a = MFMA(hs.b, bl, a);
                a = MFMA(ls.b, bh, a);
            }
        }
        acc3[k] = a;
    }
}

__global__ __launch_bounds__(256, 2) void cp_persist_k(
    const float* __restrict__ y, const float* __restrict__ sigma,
    const float* __restrict__ tau, const float* __restrict__ theta,
    const float* __restrict__ dw1, const float* __restrict__ db1,
    const float* __restrict__ dw2, const float* __restrict__ db2,
    const float* __restrict__ dw3, const float* __restrict__ db3,
    const float* __restrict__ pw1, const float* __restrict__ pb1,
    const float* __restrict__ pw2, const float* __restrict__ pb2,
    const float* __restrict__ pw3, const float* __restrict__ pb3,
    float* __restrict__ out,
    uint* bcnt, uint* flags,
    float* primal_f, float* dual_f, float* pbar1, float* dual0,
    uint* catD, uint* catP,
    __bf16* wT)
{
    __shared__ uint lds_raw[17280];          // 69120 B: hid1(9216) + aux(8064)
    __shared__ float cs[AANG], ss[AANG];
    const int tid = blockIdx.x * 256 + threadIdx.x;
    const int lane = threadIdx.x & 63;
    const int n16 = lane & 15;
    const int quad = lane >> 4;
    const int wv = threadIdx.x >> 6;
    uint bar_no = 0;

    __bf16* d1h = wT;            __bf16* d1l = d1h + 3072;
    __bf16* d2h = d1l + 3072;    __bf16* d2l = d2h + 9216;
    __bf16* d3h = d2l + 9216;    __bf16* d3l = d3h + 4608;
    __bf16* p1h = d3l + 4608;    __bf16* p1l = p1h + 3072;
    __bf16* p2h = p1l + 3072;    __bf16* p2l = p2h + 9216;
    __bf16* p3h = p2l + 9216;    __bf16* p3l = p3h + 4608;

    if (threadIdx.x < AANG) {
        double ang = (double)threadIdx.x * M_PI / (double)AANG;
        cs[threadIdx.x] = (float)cos(ang);
        ss[threadIdx.x] = (float)sin(ang);
    }

    // ---------------- setup ----------------
    for (int i = tid; i < M_P * 5; i += NT) primal_f[i] = 0.f;
    for (int i = tid; i < M_D * 5; i += NT) dual_f[i] = 0.f;
    for (int i = tid; i < M_P; i += NT) pbar1[i] = 0.f;
    for (int i = tid; i < M_D * 8; i += NT) {
        int ch = i & 7;
        catD[i] = (ch == 6) ? pack_pair(y[i >> 3]) : 0u;
    }
    for (int i = tid; i < M_P * 8; i += NT) catP[i] = 0u;
    {
        union { __bf16 b; unsigned short s; } cv;
        for (int i = tid; i < 3072; i += NT) { int tap = i >> 8, co = (i >> 3) & 31, ci = i & 7;
            float v = (tap < 9 && ci < 7) ? dw1[(tap * 7 + ci) * 32 + co] : 0.f;
            cv.b = (__bf16)v; d1h[i] = cv.b; d1l[i] = (__bf16)(v - (float)cv.b); }
        for (int i = tid; i < 9216; i += NT) { int tap = i >> 10, co = (i >> 5) & 31, ci = i & 31;
            float v = dw2[(tap * 32 + ci) * 32 + co];
            cv.b = (__bf16)v; d2h[i] = cv.b; d2l[i] = (__bf16)(v - (float)cv.b); }
        for (int i = tid; i < 4608; i += NT) { int tap = i >> 9, co = (i >> 5) & 15, ci = i & 31;
            float v = (co < 5) ? dw3[(tap * 32 + ci) * 5 + co] : 0.f;
            cv.b = (__bf16)v; d3h[i] = cv.b; d3l[i] = (__bf16)(v - (float)cv.b); }
        for (int i = tid; i < 3072; i += NT) { int tap = i >> 8, co = (i >> 3) & 31, ci = i & 7;
            float v = (tap < 9 && ci < 6) ? pw1[(tap * 6 + ci) * 32 + co] : 0.f;
            cv.b = (__bf16)v; p1h[i] = cv.b; p1l[i] = (__bf16)(v - (float)cv.b); }
        for (int i = tid; i < 9216; i += NT) { int tap = i >> 10, co = (i >> 5) & 31, ci = i & 31;
            float v = pw2[(tap * 32 + ci) * 32 + co];
            cv.b = (__bf16)v; p2h[i] = cv.b; p2l[i] = (__bf16)(v - (float)cv.b); }
        for (int i = tid; i < 4608; i += NT) { int tap = i >> 9, co = (i >> 5) & 15, ci = i & 31;
            float v = (co < 5) ? pw3[(tap * 32 + ci) * 5 + co] : 0.f;
            cv.b = (__bf16)v; p3h[i] = cv.b; p3l[i] = (__bf16)(v - (float)cv.b); }
    }

    gbar<2>(bcnt, flags, bar_no);

    for (int it = 0; it < 10; ++it) {
        // ---- S1: radon forward (cached reads of pbar1) -> catD ch5 ----
        if (tid < 2 * M_D) {
            int pix = tid >> 1, h = tid & 1;
            int d = pix & 127;
            int b = pix / (AANG * DDET);
            int a = (pix - b * AANG * DDET) >> 7;
            float c = cs[a], sn = ss[a];
            float s = (float)d - 63.5f;
            float scx = s * c, ssy = s * sn;
            const float* ib = pbar1 + b * (HHH * WWW);
            float acc = 0.f;
            int t0 = h * 91;
            for (int tt = t0; tt < t0 + 91; ++tt) {
                float t = (float)tt - 90.5f;
                float xi = (scx - t * sn) + 63.5f;
                float yi = (ssy + t * c) + 63.5f;
                float x0f = floorf(xi), y0f = floorf(yi);
                float wx = xi - x0f, wy = yi - y0f;
                int x0 = (int)x0f, y0 = (int)y0f;
                int x1 = x0 + 1, y1 = y0 + 1;
                bool xv0 = (x0 >= 0) & (x0 < WWW);
                bool xv1 = (x1 >= 0) & (x1 < WWW);
                bool yv0 = (y0 >= 0) & (y0 < HHH);
                bool yv1 = (y1 >= 0) & (y1 < HHH);
                float v00 = (yv0 & xv0) ? ib[y0 * WWW + x0] : 0.f;
                float v01 = (yv0 & xv1) ? ib[y0 * WWW + x1] : 0.f;
                float v10 = (yv1 & xv0) ? ib[y1 * WWW + x0] : 0.f;
                float v11 = (yv1 & xv1) ? ib[y1 * WWW + x1] : 0.f;
                acc += v00 * (1.f - wy) * (1.f - wx) + v01 * (1.f - wy) * wx
                     + v10 * wy * (1.f - wx) + v11 * wy * wx;
            }
            float other = __shfl_xor(acc, 1);
            if (h == 0) cstore_pair(catD + (pix * 8 + 5), (acc + other) * INV_OPN);
        }
        gbar<0>(bcnt, flags, bar_no);

        // ---- S2: fused dual conv chain (352 tiles of 12x12) ----
        if (blockIdx.x < 352) {
            int bt = blockIdx.x;
            int b = bt / 88; int r = bt - b * 88;
            int Ty = r / 11, Tx = r - Ty * 11;
            int ty0 = Ty * 12, tx0 = Tx * 12;
            f32x4 acc3[3];
            chain_convs<AANG>(catD, d1h, d1l, d2h, d2l, d3h, d3l, db1, db2,
                              lds_raw, b, ty0, tx0, acc3);
            float sg = *sigma;
            #pragma unroll
            for (int k = 0; k < 3; ++k) {
                int t = wv + 4 * k;
                if (t >= 9) break;
                int Py = t / 3, Px = t - Py * 3;
                if (n16 < 5) {
                    float bv = db3[n16];
                    int i2 = Py * 4 + quad;
                    int gy = ty0 + i2;
                    #pragma unroll
                    for (int r2 = 0; r2 < 4; ++r2) {
                        int j2 = Px * 4 + r2;
                        int gx = tx0 + j2;
                        if (gy < AANG && gx < 128) {
                            int m = b * AANG * 128 + gy * 128 + gx;
                            float v = acc3[k][r2] + bv;
                            float dn = cload_f(&dual_f[m * 5 + n16]) + sg * v;
                            cstore_f(&dual_f[m * 5 + n16], dn);
                            cstore_pair(catD + (m * 8 + n16), dn);
                            if (n16 == 0) cstore_f(&dual0[m], dn);
                        }
                    }
                }
            }
        }
        gbar<1>(bcnt, flags, bar_no);   // INV: S5 cached-reads dual0

        // ---- S3: radon adjoint (cached reads of dual0) -> catP ch5 ----
        if (tid < 2 * M_P) {
            int pix = tid >> 1, h = tid & 1;
            int x = pix & 127;
            int yv = (pix >> 7) & 127;
            int b = pix >> 14;
            float px = (float)x - 63.5f;
            float py = (float)yv - 63.5f;
            const float* sb = dual0 + b * (AANG * DDET);
            float acc = 0.f;
            int a0 = h * 48;
            for (int a = a0; a < a0 + 48; ++a) {
                float det = px * cs[a] + py * ss[a] + 63.5f;
                float dh = floorf(det);
                float w = det - dh;
                int d0 = (int)dh;
                int d1 = d0 + 1;
                float v0 = (d0 >= 0 && d0 < DDET) ? sb[a * DDET + d0] : 0.f;
                float v1 = (d1 >= 0 && d1 < DDET) ? sb[a * DDET + d1] : 0.f;
                acc += v0 * (1.f - w) + v1 * w;
            }
            float other = __shfl_xor(acc, 1);
            if (h == 0) cstore_pair(catP + (pix * 8 + 5), (acc + other) * INV_OPN);
        }
        gbar<0>(bcnt, flags, bar_no);

        // ---- S4: fused primal conv chain (484 tiles of 12x12) ----
        if (blockIdx.x < 484) {
            int bt = blockIdx.x;
            int b = bt / 121; int r = bt - b * 121;
            int Ty = r / 11, Tx = r - Ty * 11;
            int ty0 = Ty * 12, tx0 = Tx * 12;
            f32x4 acc3[3];
            chain_convs<HHH>(catP, p1h, p1l, p2h, p2l, p3h, p3l, pb1, pb2,
                             lds_raw, b, ty0, tx0, acc3);
            float ta = *tau;
            float th = *theta;
            #pragma unroll
            for (int k = 0; k < 3; ++k) {
                int t = wv + 4 * k;
                if (t >= 9) break;
                int Py = t / 3, Px = t - Py * 3;
                if (n16 < 5) {
                    float bv = pb3[n16];
                    int i2 = Py * 4 + quad;
                    int gy = ty0 + i2;
                    #pragma unroll
                    for (int r2 = 0; r2 < 4; ++r2) {
                        int j2 = Px * 4 + r2;
                        int gx = tx0 + j2;
                        if (gy < HHH && gx < 128) {
                            int m = b * HHH * 128 + gy * 128 + gx;
                            float v = acc3[k][r2] + bv;
                            float pold = cload_f(&primal_f[m * 5 + n16]);
                            float pn = pold + ta * v;
                            cstore_f(&primal_f[m * 5 + n16], pn);
                            cstore_pair(catP + (m * 8 + n16), pn);
                            if (n16 == 1) cstore_f(&pbar1[m], pn + th * (pn - pold));
                        }
                    }
                }
            }
        }
        gbar<1>(bcnt, flags, bar_no);   // INV: next S1 cached-reads pbar1
    }

    // ---- extract ch0 ----
    if (tid < M_P) out[tid] = cload_f(&primal_f[tid * 5]);
}

extern "C" void kernel_launch(void* const* d_in, const int* in_sizes, int n_in,
                              void* d_out, int out_size, void* d_ws, size_t ws_size,
                              hipStream_t stream) {
    const float* y     = (const float*)d_in[0];
    const float* sigma = (const float*)d_in[1];
    const float* tau   = (const float*)d_in[2];
    const float* theta = (const float*)d_in[3];
    const float* dw1 = (const float*)d_in[4];
    const float* db1 = (const float*)d_in[5];
    const float* dw2 = (const float*)d_in[6];
    const float* db2 = (const float*)d_in[7];
    const float* dw3 = (const float*)d_in[8];
    const float* db3 = (const float*)d_in[9];
    const float* pw1 = (const float*)d_in[10];
    const float* pb1 = (const float*)d_in[11];
    const float* pw2 = (const float*)d_in[12];
    const float* pb2 = (const float*)d_in[13];
    const float* pw3 = (const float*)d_in[14];
    const float* pb3 = (const float*)d_in[15];

    float* ws = (float*)d_ws;
    uint* bcnt  = (uint*)ws;
    uint* flags = (uint*)(ws + 128);          // NB flags, 64B apart
    float* primal_f = ws + 128 + NB * 16;     // M_P*5
    float* dual_f   = primal_f + M_P * 5;     // M_D*5
    float* pbar1    = dual_f + M_D * 5;       // M_P
    float* dual0    = pbar1 + M_P;            // M_D
    uint* catD = (uint*)(dual0 + M_D);        // M_D*8 packed pairs
    uint* catP = catD + M_D * 8;              // M_P*8
    __bf16* wT = (__bf16*)(catP + M_P * 8);   // 67584 bf16

    hipMemsetAsync(ws, 0, (size_t)(128 + NB * 16) * 4, stream);

    cp_persist_k<<<NB, 256, 0, stream>>>(
        y, sigma, tau, theta,
        dw1, db1, dw2, db2, dw3, db3,
        pw1, pb1, pw2, pb2, pw3, pb3,
        (float*)d_out, bcnt, flags,
        primal_f, dual_f, pbar1, dual0,
        catD, catP, wT);
}